// Round 14
// baseline (374.121 us; speedup 1.0000x reference)
//
#include <hip/hip_runtime.h>
#include <hip/hip_bf16.h>
#include <cstdint>
#include <cstddef>

#define BB 4
#define NN 1024
#define INDIM 128
#define DD 512
#define HH 8
#define EE 4
#define LL 3
#define HDIM 64

typedef __bf16 bf16x8 __attribute__((ext_vector_type(8)));
typedef _Float16 f16x8 __attribute__((ext_vector_type(8)));
typedef _Float16 h2 __attribute__((ext_vector_type(2)));
typedef float f32x4 __attribute__((ext_vector_type(4)));
typedef unsigned int u32x4 __attribute__((ext_vector_type(4)));

__device__ __forceinline__ unsigned short f2b(float f) {
    union { float f; unsigned int u; } v; v.f = f;
    unsigned int u = v.u;
    unsigned int r = (u + 0x7FFFu + ((u >> 16) & 1u)) >> 16;
    return (unsigned short)r;
}
__device__ __forceinline__ float b2f(unsigned int us) {
    union { unsigned int u; float f; } v; v.u = us << 16; return v.f;
}
__device__ __forceinline__ unsigned short h_bits(_Float16 h) {
    union { _Float16 h; unsigned short u; } v; v.h = h; return v.u;
}
__device__ __forceinline__ h2 u2h2(unsigned int u) {
    union { unsigned int u; h2 h; } v; v.u = u; return v.h;
}
__device__ __forceinline__ unsigned int pkrtz_u32(float a, float b) {
    auto h = __builtin_amdgcn_cvt_pkrtz(a, b);
    union { decltype(h) h; unsigned int u; } v; v.h = h; return v.u;
}

__device__ __forceinline__ void gl_lds16(const unsigned short* g, unsigned short* l) {
    __builtin_amdgcn_global_load_lds(
        (const __attribute__((address_space(1))) void*)g,
        (__attribute__((address_space(3))) void*)l, 16, 0, 0);
}

// ---------------- weight transpose+convert: W (K x N fp32) -> Wt (N x K bf16) ---------
__device__ __forceinline__ void transpose_tile_body(const float* __restrict__ src,
                                                    unsigned short* __restrict__ dst,
                                                    int K, int Nc) {
    __shared__ float tl[32][33];
    const int n0 = blockIdx.x * 32, k0 = blockIdx.y * 32;
    const int tx = threadIdx.x, ty = threadIdx.y;
#pragma unroll
    for (int r = 0; r < 4; r++) {
        int k = ty + r * 8;
        tl[k][tx] = src[(size_t)(k0 + k) * Nc + n0 + tx];
    }
    __syncthreads();
#pragma unroll
    for (int r = 0; r < 4; r++) {
        int n = ty + r * 8;
        dst[(size_t)(n0 + n) * K + k0 + tx] = f2b(tl[tx][n]);
    }
}

__global__ void k_transpose_in(const float* __restrict__ w, unsigned short* __restrict__ dst) {
    transpose_tile_body(w, dst, INDIM, DD);
}

__global__ void k_transpose_qkvo(const float* __restrict__ qw, const float* __restrict__ kw,
                                 const float* __restrict__ vw, const float* __restrict__ ow,
                                 unsigned short* __restrict__ dst) {
    int zz = blockIdx.z;
    int l = zz >> 2, tsel = zz & 3;
    const float* src = (tsel == 0) ? qw : (tsel == 1) ? kw : (tsel == 2) ? vw : ow;
    src += (size_t)l * DD * DD;
    transpose_tile_body(src, dst + (size_t)zz * DD * DD, DD, DD);
}

// ---------------- fp32 -> bf16 convert (x) ----------------
__global__ void k_convert(const float* __restrict__ src, unsigned short* __restrict__ dst,
                          long long n4) {
    long long stride = (long long)gridDim.x * blockDim.x;
    for (long long i = blockIdx.x * (long long)blockDim.x + threadIdx.x; i < n4; i += stride) {
        float4 v = reinterpret_cast<const float4*>(src)[i];
        uint2 o;
        o.x = (unsigned)f2b(v.x) | ((unsigned)f2b(v.y) << 16);
        o.y = (unsigned)f2b(v.z) | ((unsigned)f2b(v.w) << 16);
        reinterpret_cast<uint2*>(dst)[i] = o;
    }
}

// ---------------- edges fp32 -> tile-blocked F16 layout (ebt2) ----------------
// Tile = (b, it, jb): 8 KB of 16i x 64j x 4e f16; attn slot (c, lane) holds the quad
// for i = it*16 + (lane&15), j = jb*64 + (c>>1)*16 + (lane>>4)*4 + (c&1)*2 + q.
__global__ __launch_bounds__(256) void k_convert_e2(const float* __restrict__ src,
                                                    unsigned short* __restrict__ dst) {
    __shared__ unsigned short tl[4096];   // 8 KB tile
    const int tile = blockIdx.x;          // (b*64 + it)*16 + jb
    const int jb = tile & 15;
    const int it = (tile >> 4) & 63;
    const int b  = tile >> 10;
    const int tid = threadIdx.x;
    const int f4 = tid & 63;              // j_off within tile
    const int r0 = tid >> 6;              // 0..3
    const int jt = f4 >> 4, w16 = f4 & 15;
    const int lh = w16 >> 2, rr = w16 & 3;
    const int c = jt * 2 + (rr >> 1), q = rr & 1;
#pragma unroll
    for (int rd = 0; rd < 4; rd++) {
        const int lm = rd * 4 + r0;       // i within tile
        const float4 e = *reinterpret_cast<const float4*>(
            &src[(((size_t)b * NN + it * 16 + lm) * NN + jb * 64 + f4) * EE]);
        uint2 o;
        o.x = pkrtz_u32(e.x, e.y);
        o.y = pkrtz_u32(e.z, e.w);
        const int slot = c * 128 + (lh * 16 + lm) * 2 + q;   // uint2 units
        *reinterpret_cast<uint2*>(&tl[slot * 4]) = o;
    }
    __syncthreads();
    u32x4* g = reinterpret_cast<u32x4*>(dst) + (size_t)tile * 512;
    const u32x4* s = reinterpret_cast<const u32x4*>(tl);
    __builtin_nontemporal_store(s[tid], g + tid);
    __builtin_nontemporal_store(s[tid + 256], g + tid + 256);
}

// ---------------- bf16 MFMA GEMM: 128x128 tile (m97 structure), global_load_lds ------
__global__ __launch_bounds__(256) void k_gemm(
    const unsigned short* __restrict__ A,
    const unsigned short* __restrict__ Wt0, size_t wstride,
    const float* __restrict__ bias0, const float* __restrict__ bias1, const float* __restrict__ bias2,
    float* __restrict__ outf,
    unsigned short* __restrict__ outb, size_t ostride,
    const float* __restrict__ resid,
    int Kd)
{
    __shared__ __align__(16) unsigned short As[128 * 32];
    __shared__ __align__(16) unsigned short Bs[128 * 32];
    const int tid = threadIdx.x;
    const int lane = tid & 63, wv = tid >> 6;
    const int wr = wv >> 1, wc = wv & 1;
    const int lm = lane & 15, lh = lane >> 4;
    const int m0 = blockIdx.y * 128, n0 = blockIdx.x * 128;
    const int z = blockIdx.z;
    const unsigned short* Wt = Wt0 + (size_t)z * wstride;
    const float* bias = (z == 0) ? bias0 : (z == 1) ? bias1 : bias2;

    f32x4 acc[4][4] = {};

    const int o0 = tid * 16;
    const int row0 = o0 >> 6, col0 = (o0 & 63) >> 1;
    const int row1 = row0 + 64;

    for (int k0 = 0; k0 < Kd; k0 += 32) {
        __syncthreads();
        gl_lds16(A  + (size_t)(m0 + row0) * Kd + k0 + col0, As + (o0 >> 1));
        gl_lds16(A  + (size_t)(m0 + row1) * Kd + k0 + col0, As + 2048 + (o0 >> 1));
        gl_lds16(Wt + (size_t)(n0 + row0) * Kd + k0 + col0, Bs + (o0 >> 1));
        gl_lds16(Wt + (size_t)(n0 + row1) * Kd + k0 + col0, Bs + 2048 + (o0 >> 1));
        __syncthreads();

        bf16x8 af[4], bfg[4];
#pragma unroll
        for (int mi = 0; mi < 4; mi++)
            af[mi] = *reinterpret_cast<const bf16x8*>(&As[(wr * 64 + mi * 16 + lm) * 32 + lh * 8]);
#pragma unroll
        for (int nj = 0; nj < 4; nj++)
            bfg[nj] = *reinterpret_cast<const bf16x8*>(&Bs[(wc * 64 + nj * 16 + lm) * 32 + lh * 8]);
        __builtin_amdgcn_s_setprio(1);
#pragma unroll
        for (int mi = 0; mi < 4; mi++)
#pragma unroll
            for (int nj = 0; nj < 4; nj++)
                acc[mi][nj] = __builtin_amdgcn_mfma_f32_16x16x32_bf16(af[mi], bfg[nj], acc[mi][nj], 0, 0, 0);
        __builtin_amdgcn_s_setprio(0);
    }

#pragma unroll
    for (int mi = 0; mi < 4; mi++) {
#pragma unroll
        for (int nj = 0; nj < 4; nj++) {
#pragma unroll
            for (int r = 0; r < 4; r++) {
                int i = m0 + wr * 64 + mi * 16 + lh * 4 + r;
                int j = n0 + wc * 64 + nj * 16 + lm;
                float val = acc[mi][nj][r] + bias[j];
                size_t oidx = (size_t)i * DD + j;
                if (resid) val += resid[oidx];
                if (outf) outf[oidx] = val;
                if (outb) outb[(size_t)z * ostride + oidx] = f2b(val);
            }
        }
    }
}

// ---------------- V transpose+convert: vb (B*N,D) bf16 -> vt (B,H,HD,N) F16 ----------
__global__ __launch_bounds__(256) void k_transpose_v(const unsigned short* __restrict__ vb,
                                                     unsigned short* __restrict__ vt) {
    __shared__ unsigned short tl[64 * 72];
    const int bh = blockIdx.x;
    const int b = bh >> 3, h = bh & 7;
    const int n0 = blockIdx.y * 64;
    const int t = threadIdx.x;
    {
        int n = t >> 2, seg = t & 3;
        const unsigned short* src = vb + ((size_t)b * NN + n0 + n) * DD + h * HDIM + seg * 16;
        int4 c0 = *reinterpret_cast<const int4*>(src);
        int4 c1 = *reinterpret_cast<const int4*>(src + 8);
        *reinterpret_cast<int4*>(&tl[n * 72 + seg * 16]) = c0;
        *reinterpret_cast<int4*>(&tl[n * 72 + seg * 16 + 8]) = c1;
    }
    __syncthreads();
    {
        int d = t & 63, nb = t >> 6;
        union { unsigned short s[8]; int4 v; } pk0, pk1;
#pragma unroll
        for (int q = 0; q < 8; q++) pk0.s[q] = h_bits((_Float16)b2f(tl[(nb * 16 + q) * 72 + d]));
#pragma unroll
        for (int q = 0; q < 8; q++) pk1.s[q] = h_bits((_Float16)b2f(tl[(nb * 16 + 8 + q) * 72 + d]));
        unsigned short* dst = vt + (((size_t)b * HH + h) * HDIM + d) * NN + n0 + nb * 16;
        *reinterpret_cast<int4*>(dst) = pk0.v;
        *reinterpret_cast<int4*>(dst + 8) = pk1.v;
    }
}

// ---------------- fused attention G=2: defer-max + setprio, shared p_lds slab --------
// Grid 512 linear: xcd=lin&7, s=lin>>3, combo=xcd*2+(s>>5) = js*4+b, itg=s&31.
// Per j-iter: K,V loaded once, consumed by TWO independent QK/softmax/PV chains.
// Defer-max (T13): skip rescale when all rows' tile-max <= m_run + 8 (log2 domain).
template <int JS>
__global__ __launch_bounds__(512) void k_attn_g2(
    const unsigned short* __restrict__ qb,
    const unsigned short* __restrict__ kb,
    const unsigned short* __restrict__ vt,
    const unsigned short* __restrict__ ebt,  // f16 tile-blocked
    const float* __restrict__ ew,            // (L,E,H)
    const float* __restrict__ ebias,         // (L,H)
    int layer,
    unsigned short* __restrict__ outpb,      // (JS,B,N,D) bf16 partial O
    float2* __restrict__ mlp)                // (JS,B,H,N) partial (m,l)
{
    __shared__ __align__(16) unsigned short e_lds[2][2][4096];  // 32 KB
    __shared__ unsigned short p_lds[8][16 * 68];                // 17.4 KB (shared across g)
    const int lin = blockIdx.x;
    const int xcd = lin & 7;
    const int s   = lin >> 3;
    const int combo = xcd * 2 + (s >> 5);    // = js*4 + b
    const int itg = s & 31;
    const int b  = combo & 3;
    const int js = combo >> 2;
    const int tid = threadIdx.x;
    const int lane = tid & 63, wv = tid >> 6;
    const int h = wv;
    const int lm = lane & 15, lh = lane >> 4;

    const float LOG2E = 1.44269504f;
    const float ebh = ebias[layer * HH + h] * LOG2E;
    const float qscale = 0.125f * LOG2E;
    h2 w01, w23;
    w01.x = (_Float16)(ew[(layer * EE + 0) * HH + h] * LOG2E);
    w01.y = (_Float16)(ew[(layer * EE + 1) * HH + h] * LOG2E);
    w23.x = (_Float16)(ew[(layer * EE + 2) * HH + h] * LOG2E);
    w23.y = (_Float16)(ew[(layer * EE + 3) * HH + h] * LOG2E);

    bf16x8 aq[2][2];
#pragma unroll
    for (int g = 0; g < 2; g++) {
        const unsigned short* qrow =
            qb + ((size_t)(b * NN) + itg * 32 + g * 16 + lm) * DD + h * HDIM + lh * 8;
        aq[g][0] = *reinterpret_cast<const bf16x8*>(qrow);
        aq[g][1] = *reinterpret_cast<const bf16x8*>(qrow + 32);
    }

    f32x4 acc[2][4] = {};
    float m_run[2] = {-1e30f, -1e30f}, l_run[2] = {0.f, 0.f};

    constexpr int NITER = (NN / JS) / 64;
    const int jlo = js * (NN / JS);
    const int jb0 = jlo >> 6;
    const unsigned short* etile0 = ebt + ((size_t)((b * 64 + itg * 2 + 0) * 16 + jb0)) * 4096;
    const unsigned short* etile1 = ebt + ((size_t)((b * 64 + itg * 2 + 1) * 16 + jb0)) * 4096;
    const unsigned short* kptr = kb + ((size_t)(b * NN) + jlo + lm) * DD + h * HDIM + lh * 8;
    const unsigned short* vptr = vt + (((size_t)(b * HH) + h) * HDIM + lm) * NN + jlo + lh * 8;

    // prologue: DMA both g-tiles of j-tile 0
    gl_lds16(etile0 + tid * 8, &e_lds[0][0][tid * 8]);
    gl_lds16(etile1 + tid * 8, &e_lds[0][1][tid * 8]);
    __syncthreads();

#pragma unroll
    for (int i = 0; i < NITER; i++) {
        const int cur = i & 1;
        if (i + 1 < NITER) {
            gl_lds16(etile0 + (size_t)(i + 1) * 4096 + tid * 8, &e_lds[cur ^ 1][0][tid * 8]);
            gl_lds16(etile1 + (size_t)(i + 1) * 4096 + tid * 8, &e_lds[cur ^ 1][1][tid * 8]);
        }

        // ---- K and V for this j-tile (shared by both chains) ----
        bf16x8 kf[8];
        f16x8  vf[8];
#pragma unroll
        for (int jt = 0; jt < 4; jt++) {
            const unsigned short* kr = kptr + (size_t)i * 64 * DD + (size_t)jt * 16 * DD;
            kf[jt * 2]     = *reinterpret_cast<const bf16x8*>(kr);
            kf[jt * 2 + 1] = *reinterpret_cast<const bf16x8*>(kr + 32);
        }
#pragma unroll
        for (int kc = 0; kc < 2; kc++)
#pragma unroll
            for (int dt = 0; dt < 4; dt++)
                vf[kc * 4 + dt] = *reinterpret_cast<const f16x8*>(
                    vptr + (size_t)dt * 16 * NN + i * 64 + kc * 32);

        // ---- two independent chains (p_lds slab reused sequentially per g) ----
#pragma unroll
        for (int g = 0; g < 2; g++) {
            f32x4 sreg[4];
            __builtin_amdgcn_s_setprio(1);
#pragma unroll
            for (int jt = 0; jt < 4; jt++) {
                f32x4 t = {};
                t = __builtin_amdgcn_mfma_f32_16x16x32_bf16(kf[jt * 2], aq[g][0], t, 0, 0, 0);
                t = __builtin_amdgcn_mfma_f32_16x16x32_bf16(kf[jt * 2 + 1], aq[g][1], t, 0, 0, 0);
                sreg[jt] = t;
            }
            __builtin_amdgcn_s_setprio(0);

            float pv[16];
#pragma unroll
            for (int c = 0; c < 8; c++) {
                const uint4 ee = *reinterpret_cast<const uint4*>(
                    &e_lds[cur][g][(c * 64 + lane) * 8]);
                const int jt = c >> 1, r0 = (c & 1) * 2;
                pv[jt * 4 + r0] = fmaf(sreg[jt][r0], qscale,
                    __builtin_amdgcn_fdot2(u2h2(ee.x), w01,
                        __builtin_amdgcn_fdot2(u2h2(ee.y), w23, ebh, false), false));
                pv[jt * 4 + r0 + 1] = fmaf(sreg[jt][r0 + 1], qscale,
                    __builtin_amdgcn_fdot2(u2h2(ee.z), w01,
                        __builtin_amdgcn_fdot2(u2h2(ee.w), w23, ebh, false), false));
            }

            float mt = pv[0];
#pragma unroll
            for (int q = 1; q < 16; q++) mt = fmaxf(mt, pv[q]);
            mt = fmaxf(mt, __shfl_xor(mt, 16));
            mt = fmaxf(mt, __shfl_xor(mt, 32));
            // defer-max (T13): only rescale when some row grew past m_run + 8
            if (!__all(mt - m_run[g] <= 8.f)) {
                float mn = fmaxf(m_run[g], mt);
                float corr = __builtin_amdgcn_exp2f(m_run[g] - mn);
                m_run[g] = mn;
                l_run[g] *= corr;
#pragma unroll
                for (int dt = 0; dt < 4; dt++)
#pragma unroll
                    for (int r = 0; r < 4; r++) acc[g][dt][r] *= corr;
            }
            float ls = 0.f;
#pragma unroll
            for (int q = 0; q < 16; q++) {
                pv[q] = __builtin_amdgcn_exp2f(pv[q] - m_run[g]);
                ls += pv[q];
            }
            ls += __shfl_xor(ls, 16);
            ls += __shfl_xor(ls, 32);
            l_run[g] += ls;

#pragma unroll
            for (int jt = 0; jt < 4; jt++) {
                uint2 u;
                u.x = pkrtz_u32(pv[jt * 4 + 0], pv[jt * 4 + 1]);
                u.y = pkrtz_u32(pv[jt * 4 + 2], pv[jt * 4 + 3]);
                *reinterpret_cast<uint2*>(&p_lds[wv][lm * 68 + jt * 16 + lh * 4]) = u;
            }

            __builtin_amdgcn_s_setprio(1);
#pragma unroll
            for (int kc = 0; kc < 2; kc++) {
                f16x8 pb = *reinterpret_cast<const f16x8*>(
                    &p_lds[wv][lm * 68 + kc * 32 + lh * 8]);
#pragma unroll
                for (int dt = 0; dt < 4; dt++)
                    acc[g][dt] = __builtin_amdgcn_mfma_f32_16x16x32_f16(
                        vf[kc * 4 + dt], pb, acc[g][dt], 0, 0, 0);
            }
            __builtin_amdgcn_s_setprio(0);
        }

        __syncthreads();
    }

#pragma unroll
    for (int g = 0; g < 2; g++) {
        const int irow = itg * 32 + g * 16 + lm;
#pragma unroll
        for (int dt = 0; dt < 4; dt++) {
            union { unsigned short us[4]; uint2 u; } pk;
#pragma unroll
            for (int r = 0; r < 4; r++) pk.us[r] = f2b(acc[g][dt][r]);
            *reinterpret_cast<uint2*>(
                &outpb[((size_t)(js * BB + b) * NN + irow) * DD + h * HDIM + dt * 16 + lh * 4]) = pk.u;
        }
        if (lh == 0)
            mlp[((size_t)(js * BB + b) * HH + h) * NN + irow] = make_float2(m_run[g], l_run[g]);
    }
}

// ---------------- fallback fused attention (fp32 edges, unpipelined) ------------------
__global__ __launch_bounds__(512) void k_attn_f(
    const unsigned short* __restrict__ qb,
    const unsigned short* __restrict__ kb,
    const unsigned short* __restrict__ vt,
    const float* __restrict__ edges,
    const float* __restrict__ ew, const float* __restrict__ ebias,
    int layer,
    unsigned short* __restrict__ attnob)
{
    __shared__ unsigned short p_lds[8][16 * 68];
    const int b = blockIdx.y;
    const int i0 = blockIdx.x * 16;
    const int tid = threadIdx.x;
    const int lane = tid & 63, wv = tid >> 6;
    const int h = wv;
    const int lm = lane & 15, lh = lane >> 4;

    const float LOG2E = 1.44269504f;
    const float ew0 = ew[(layer * EE + 0) * HH + h] * LOG2E;
    const float ew1 = ew[(layer * EE + 1) * HH + h] * LOG2E;
    const float ew2 = ew[(layer * EE + 2) * HH + h] * LOG2E;
    const float ew3 = ew[(layer * EE + 3) * HH + h] * LOG2E;
    const float ebh = ebias[layer * HH + h] * LOG2E;
    const float qscale = 0.125f * LOG2E;

    const unsigned short* qrow = qb + ((size_t)(b * NN) + i0 + lm) * DD + h * HDIM + lh * 8;
    const bf16x8 aq0 = *reinterpret_cast<const bf16x8*>(qrow);
    const bf16x8 aq1 = *reinterpret_cast<const bf16x8*>(qrow + 32);

    f32x4 acc[4] = {};
    float m_run = -1e30f, l_run = 0.f;
    const float4* ef4 = (const float4*)edges;
    const size_t erowbase = ((size_t)b * NN + i0 + lm) * NN;

    for (int j0 = 0; j0 < NN; j0 += 64) {
        f32x4 sreg[4];
#pragma unroll
        for (int jt = 0; jt < 4; jt++) {
            const unsigned short* krow =
                kb + ((size_t)(b * NN) + j0 + jt * 16 + lm) * DD + h * HDIM + lh * 8;
            bf16x8 k0 = *reinterpret_cast<const bf16x8*>(krow);
            bf16x8 k1 = *reinterpret_cast<const bf16x8*>(krow + 32);
            f32x4 t = {};
            t = __builtin_amdgcn_mfma_f32_16x16x32_bf16(k0, aq0, t, 0, 0, 0);
            t = __builtin_amdgcn_mfma_f32_16x16x32_bf16(k1, aq1, t, 0, 0, 0);
            sreg[jt] = t;
        }
        float pv[16];
#pragma unroll
        for (int jt = 0; jt < 4; jt++) {
            const size_t jbase = erowbase + j0 + jt * 16 + lh * 4;
#pragma unroll
            for (int r = 0; r < 4; r++) {
                float4 e = ef4[jbase + r];
                pv[jt * 4 + r] = sreg[jt][r] * qscale
                    + e.x * ew0 + e.y * ew1 + e.z * ew2 + e.w * ew3 + ebh;
            }
        }
        float mt = pv[0];
#pragma unroll
        for (int q = 1; q < 16; q++) mt = fmaxf(mt, pv[q]);
        mt = fmaxf(mt, __shfl_xor(mt, 16));
        mt = fmaxf(mt, __shfl_xor(mt, 32));
        float mn = fmaxf(m_run, mt);
        float corr = __builtin_amdgcn_exp2f(m_run - mn);
        m_run = mn;
        float ls = 0.f;
#pragma unroll
        for (int q = 0; q < 16; q++) {
            pv[q] = __builtin_amdgcn_exp2f(pv[q] - mn);
            ls += pv[q];
        }
        ls += __shfl_xor(ls, 16);
        ls += __shfl_xor(ls, 32);
        l_run = l_run * corr + ls;
#pragma unroll
        for (int jt = 0; jt < 4; jt++) {
            uint2 u;
            u.x = pkrtz_u32(pv[jt * 4 + 0], pv[jt * 4 + 1]);
            u.y = pkrtz_u32(pv[jt * 4 + 2], pv[jt * 4 + 3]);
            *reinterpret_cast<uint2*>(&p_lds[wv][lm * 68 + jt * 16 + lh * 4]) = u;
        }
#pragma unroll
        for (int dt = 0; dt < 4; dt++)
#pragma unroll
            for (int r = 0; r < 4; r++) acc[dt][r] *= corr;
#pragma unroll
        for (int kc = 0; kc < 2; kc++) {
            f16x8 pb = *reinterpret_cast<const f16x8*>(&p_lds[wv][lm * 68 + kc * 32 + lh * 8]);
#pragma unroll
            for (int dt = 0; dt < 4; dt++) {
                f16x8 av = *reinterpret_cast<const f16x8*>(
                    vt + (((size_t)(b * HH) + h) * HDIM + dt * 16 + lm) * NN + j0 + kc * 32 + lh * 8);
                acc[dt] = __builtin_amdgcn_mfma_f32_16x16x32_f16(av, pb, acc[dt], 0, 0, 0);
            }
        }
    }
    const float inv = 1.f / l_run;
#pragma unroll
    for (int dt = 0; dt < 4; dt++) {
        union { unsigned short us[4]; uint2 u; } pk;
#pragma unroll
        for (int r = 0; r < 4; r++) pk.us[r] = f2b(acc[dt][r] * inv);
        *reinterpret_cast<uint2*>(
            &attnob[((size_t)(b * NN) + i0 + lm) * DD + h * HDIM + dt * 16 + lh * 4]) = pk.u;
    }
}

// ---------------- split-j reduce: combine JS bf16 partials -> bf16 attnob -------------
template <int JS>
__global__ __launch_bounds__(256) void k_attnred(
    const unsigned short* __restrict__ outpb, const float2* __restrict__ mlp,
    unsigned short* __restrict__ attnob)
{
    const int tid = blockIdx.x * 256 + threadIdx.x;   // (b,n,h,dc) dc = d/4
    const int dc = tid & 15;
    const int h = (tid >> 4) & 7;
    const int n = (tid >> 7) & (NN - 1);
    const int b = tid >> 17;
    float ms[JS], lsv[JS];
    float mstar = -1e30f;
#pragma unroll
    for (int s2 = 0; s2 < JS; s2++) {
        float2 ml = mlp[((size_t)(s2 * BB + b) * HH + h) * NN + n];
        ms[s2] = ml.x; lsv[s2] = ml.y;
        mstar = fmaxf(mstar, ml.x);
    }
    float lstar = 0.f;
    float o0 = 0.f, o1 = 0.f, o2 = 0.f, o3 = 0.f;
#pragma unroll
    for (int s2 = 0; s2 < JS; s2++) {
        float w = __builtin_amdgcn_exp2f(ms[s2] - mstar);
        lstar += w * lsv[s2];
        uint2 a = *reinterpret_cast<const uint2*>(
            &outpb[((size_t)(s2 * BB + b) * NN + n) * DD + h * HDIM + dc * 4]);
        o0 += w * b2f(a.x & 0xffffu); o1 += w * b2f(a.x >> 16);
        o2 += w * b2f(a.y & 0xffffu); o3 += w * b2f(a.y >> 16);
    }
    const float inv = 1.f / lstar;
    union { unsigned short us[4]; uint2 u; } pk;
    pk.us[0] = f2b(o0 * inv); pk.us[1] = f2b(o1 * inv);
    pk.us[2] = f2b(o2 * inv); pk.us[3] = f2b(o3 * inv);
    *reinterpret_cast<uint2*>(&attnob[((size_t)b * NN + n) * DD + h * HDIM + dc * 4]) = pk.u;
}

// ---------------- final layernorm: one wave per row ----------------
__global__ __launch_bounds__(64) void k_ln(const float* __restrict__ hbuf,
                                           const float* __restrict__ g,
                                           const float* __restrict__ bta,
                                           float* __restrict__ out) {
    const int row = blockIdx.x;
    const int lane = threadIdx.x;
    const float* hr = hbuf + (size_t)row * DD;
    float4 v0 = reinterpret_cast<const float4*>(hr)[lane * 2];
    float4 v1 = reinterpret_cast<const float4*>(hr)[lane * 2 + 1];
    float vals[8] = {v0.x, v0.y, v0.z, v0.w, v1.x, v1.y, v1.z, v1.w};
    float sum = 0.f, sq = 0.f;
#pragma unroll
    for (int q = 0; q < 8; q++) { sum += vals[q]; sq += vals[q] * vals[q]; }
#pragma unroll
    for (int m = 1; m <= 32; m <<= 1) {
        sum += __shfl_xor(sum, m);
        sq += __shfl_xor(sq, m);
    }
    float mu = sum * (1.f / DD);
    float var = sq * (1.f / DD) - mu * mu;
    float rs = rsqrtf(var + 1e-5f);
    const float* gp = g + lane * 8;
    const float* bp = bta + lane * 8;
    float* op = out + (size_t)row * DD + lane * 8;
#pragma unroll
    for (int q = 0; q < 8; q++) op[q] = (vals[q] - mu) * rs * gp[q] + bp[q];
}

extern "C" void kernel_launch(void* const* d_in, const int* in_sizes, int n_in,
                              void* d_out, int out_size, void* d_ws, size_t ws_size,
                              hipStream_t stream) {
    (void)in_sizes; (void)n_in; (void)out_size;
    const float* x     = (const float*)d_in[0];
    const float* edges = (const float*)d_in[1];
    const float* in_w  = (const float*)d_in[2];
    const float* in_b  = (const float*)d_in[3];
    const float* qw    = (const float*)d_in[4];
    const float* qbias = (const float*)d_in[5];
    const float* kw    = (const float*)d_in[6];
    const float* kbias = (const float*)d_in[7];
    const float* vw    = (const float*)d_in[8];
    const float* vbias = (const float*)d_in[9];
    const float* ow    = (const float*)d_in[10];
    const float* obias = (const float*)d_in[11];
    const float* ew    = (const float*)d_in[12];
    const float* ebias = (const float*)d_in[13];
    const float* ln_g  = (const float*)d_in[14];
    const float* ln_b  = (const float*)d_in[15];
    float* out = (float*)d_out;

    constexpr int JS = 4;
    char* ws = (char*)d_ws;
    size_t off = 0;
    auto alloc = [&](size_t bytes) -> void* {
        void* p = ws + off;
        off += (bytes + 255) & ~(size_t)255;
        return p;
    };
    const size_t M = (size_t)BB * NN;            // 4096
    float*          hbuf  = (float*)         alloc(M * DD * 4);
    unsigned short* hb    = (unsigned short*)alloc(M * DD * 2);
    unsigned short* xb    = (unsigned short*)alloc(M * INDIM * 2);
    unsigned short* wt_in = (unsigned short*)alloc((size_t)DD * INDIM * 2);
    unsigned short* wt    = (unsigned short*)alloc((size_t)12 * DD * DD * 2);
    unsigned short* qkvb  = (unsigned short*)alloc((size_t)3 * M * DD * 2);
    unsigned short* vtb   = (unsigned short*)alloc(M * DD * 2);
    unsigned short* attnob= (unsigned short*)alloc(M * DD * 2);
    const size_t edgeElems = (size_t)BB * NN * NN * EE;            // 16.8M
    unsigned short* ebt   = (unsigned short*)alloc(edgeElems * 2); // 33.5 MB tile-blocked f16
    const bool use_ebf = (off <= ws_size);
    unsigned short* outpb = (unsigned short*)alloc((size_t)JS * M * DD * 2);   // 16.8 MB
    float2*         mlp   = (float2*)        alloc((size_t)JS * BB * HH * NN * 8);
    const bool use_split = (off <= ws_size);
    const size_t BND = M * DD;

    // weight prep + input/edge conversion
    k_transpose_in<<<dim3(DD / 32, INDIM / 32), dim3(32, 8), 0, stream>>>(in_w, wt_in);
    k_transpose_qkvo<<<dim3(DD / 32, DD / 32, 12), dim3(32, 8), 0, stream>>>(qw, kw, vw, ow, wt);
    k_convert<<<dim3(512), dim3(256), 0, stream>>>(x, xb, (long long)(M * INDIM / 4));
    if (use_ebf && use_split)
        k_convert_e2<<<dim3(4096), dim3(256), 0, stream>>>(edges, ebt);

    // input projection: h = x @ in_w + in_b  (writes fp32 h and bf16 hb)
    k_gemm<<<dim3(4, 32, 1), dim3(256), 0, stream>>>(
        xb, wt_in, (size_t)0, in_b, in_b, in_b, hbuf, hb, (size_t)0, (const float*)nullptr, INDIM);

    for (int l = 0; l < LL; l++) {
        k_gemm<<<dim3(4, 32, 3), dim3(256), 0, stream>>>(
            hb, wt + (size_t)(l * 4) * DD * DD, (size_t)DD * DD,
            qbias + l * DD, kbias + l * DD, vbias + l * DD,
            (float*)nullptr, qkvb, BND, (const float*)nullptr, DD);
        k_transpose_v<<<dim3(32, 16), dim3(256), 0, stream>>>(qkvb + 2 * BND, vtb);

        if (use_ebf && use_split) {
            k_attn_g2<JS><<<dim3(512), dim3(512), 0, stream>>>(
                qkvb, qkvb + BND, vtb, ebt, ew, ebias, l, outpb, mlp);
            k_attnred<JS><<<dim3((unsigned)(M * HH * 16 / 256)), dim3(256), 0, stream>>>(
                outpb, mlp, attnob);
        } else {
            k_attn_f<<<dim3(64, BB, 1), dim3(512), 0, stream>>>(
                qkvb, qkvb + BND, vtb, edges, ew, ebias, l, attnob);
        }

        k_gemm<<<dim3(4, 32, 1), dim3(256), 0, stream>>>(
            attnob, wt + (size_t)(l * 4 + 3) * DD * DD, (size_t)0,
            obias + l * DD, obias + l * DD, obias + l * DD,
            hbuf, hb, (size_t)0, hbuf, DD);
    }

    k_ln<<<dim3((unsigned)M), dim3(64), 0, stream>>>(hbuf, ln_g, ln_b, out);
}

// Round 15
// 351.400 us; speedup vs baseline: 1.0647x; 1.0647x over previous
//
#include <hip/hip_runtime.h>
#include <hip/hip_bf16.h>
#include <cstdint>
#include <cstddef>

#define BB 4
#define NN 1024
#define INDIM 128
#define DD 512
#define HH 8
#define EE 4
#define LL 3
#define HDIM 64

typedef __bf16 bf16x8 __attribute__((ext_vector_type(8)));
typedef _Float16 f16x8 __attribute__((ext_vector_type(8)));
typedef _Float16 h2 __attribute__((ext_vector_type(2)));
typedef float f32x4 __attribute__((ext_vector_type(4)));
typedef unsigned int u32x4 __attribute__((ext_vector_type(4)));

__device__ __forceinline__ unsigned short f2b(float f) {
    union { float f; unsigned int u; } v; v.f = f;
    unsigned int u = v.u;
    unsigned int r = (u + 0x7FFFu + ((u >> 16) & 1u)) >> 16;
    return (unsigned short)r;
}
__device__ __forceinline__ float b2f(unsigned int us) {
    union { unsigned int u; float f; } v; v.u = us << 16; return v.f;
}
__device__ __forceinline__ unsigned short h_bits(_Float16 h) {
    union { _Float16 h; unsigned short u; } v; v.h = h; return v.u;
}
__device__ __forceinline__ h2 u2h2(unsigned int u) {
    union { unsigned int u; h2 h; } v; v.u = u; return v.h;
}
__device__ __forceinline__ unsigned int pkrtz_u32(float a, float b) {
    auto h = __builtin_amdgcn_cvt_pkrtz(a, b);
    union { decltype(h) h; unsigned int u; } v; v.h = h; return v.u;
}

__device__ __forceinline__ void gl_lds16(const unsigned short* g, unsigned short* l) {
    __builtin_amdgcn_global_load_lds(
        (const __attribute__((address_space(1))) void*)g,
        (__attribute__((address_space(3))) void*)l, 16, 0, 0);
}

// ---------------- weight transpose+convert: W (K x N fp32) -> Wt (N x K bf16) ---------
__device__ __forceinline__ void transpose_tile_body(const float* __restrict__ src,
                                                    unsigned short* __restrict__ dst,
                                                    int K, int Nc) {
    __shared__ float tl[32][33];
    const int n0 = blockIdx.x * 32, k0 = blockIdx.y * 32;
    const int tx = threadIdx.x, ty = threadIdx.y;
#pragma unroll
    for (int r = 0; r < 4; r++) {
        int k = ty + r * 8;
        tl[k][tx] = src[(size_t)(k0 + k) * Nc + n0 + tx];
    }
    __syncthreads();
#pragma unroll
    for (int r = 0; r < 4; r++) {
        int n = ty + r * 8;
        dst[(size_t)(n0 + n) * K + k0 + tx] = f2b(tl[tx][n]);
    }
}

__global__ void k_transpose_in(const float* __restrict__ w, unsigned short* __restrict__ dst) {
    transpose_tile_body(w, dst, INDIM, DD);
}

__global__ void k_transpose_qkvo(const float* __restrict__ qw, const float* __restrict__ kw,
                                 const float* __restrict__ vw, const float* __restrict__ ow,
                                 unsigned short* __restrict__ dst) {
    int zz = blockIdx.z;
    int l = zz >> 2, tsel = zz & 3;
    const float* src = (tsel == 0) ? qw : (tsel == 1) ? kw : (tsel == 2) ? vw : ow;
    src += (size_t)l * DD * DD;
    transpose_tile_body(src, dst + (size_t)zz * DD * DD, DD, DD);
}

// ---------------- fp32 -> bf16 convert (x) ----------------
__global__ void k_convert(const float* __restrict__ src, unsigned short* __restrict__ dst,
                          long long n4) {
    long long stride = (long long)gridDim.x * blockDim.x;
    for (long long i = blockIdx.x * (long long)blockDim.x + threadIdx.x; i < n4; i += stride) {
        float4 v = reinterpret_cast<const float4*>(src)[i];
        uint2 o;
        o.x = (unsigned)f2b(v.x) | ((unsigned)f2b(v.y) << 16);
        o.y = (unsigned)f2b(v.z) | ((unsigned)f2b(v.w) << 16);
        reinterpret_cast<uint2*>(dst)[i] = o;
    }
}

// ---------------- edges fp32 -> tile-blocked F16 layout (ebt2) ----------------
// Tile = (b, it, jb): 8 KB of 16i x 64j x 4e f16; attn slot (c, lane) holds the quad
// for i = it*16 + (lane&15), j = jb*64 + (c>>1)*16 + (lane>>4)*4 + (c&1)*2 + q.
__global__ __launch_bounds__(256) void k_convert_e2(const float* __restrict__ src,
                                                    unsigned short* __restrict__ dst) {
    __shared__ unsigned short tl[4096];   // 8 KB tile
    const int tile = blockIdx.x;          // (b*64 + it)*16 + jb
    const int jb = tile & 15;
    const int it = (tile >> 4) & 63;
    const int b  = tile >> 10;
    const int tid = threadIdx.x;
    const int f4 = tid & 63;              // j_off within tile
    const int r0 = tid >> 6;              // 0..3
    const int jt = f4 >> 4, w16 = f4 & 15;
    const int lh = w16 >> 2, rr = w16 & 3;
    const int c = jt * 2 + (rr >> 1), q = rr & 1;
#pragma unroll
    for (int rd = 0; rd < 4; rd++) {
        const int lm = rd * 4 + r0;       // i within tile
        const float4 e = *reinterpret_cast<const float4*>(
            &src[(((size_t)b * NN + it * 16 + lm) * NN + jb * 64 + f4) * EE]);
        uint2 o;
        o.x = pkrtz_u32(e.x, e.y);
        o.y = pkrtz_u32(e.z, e.w);
        const int slot = c * 128 + (lh * 16 + lm) * 2 + q;   // uint2 units
        *reinterpret_cast<uint2*>(&tl[slot * 4]) = o;
    }
    __syncthreads();
    u32x4* g = reinterpret_cast<u32x4*>(dst) + (size_t)tile * 512;
    const u32x4* s = reinterpret_cast<const u32x4*>(tl);
    __builtin_nontemporal_store(s[tid], g + tid);
    __builtin_nontemporal_store(s[tid + 256], g + tid + 256);
}

// ---------------- bf16 MFMA GEMM: 128x128 tile (m97 structure), global_load_lds ------
__global__ __launch_bounds__(256) void k_gemm(
    const unsigned short* __restrict__ A,
    const unsigned short* __restrict__ Wt0, size_t wstride,
    const float* __restrict__ bias0, const float* __restrict__ bias1, const float* __restrict__ bias2,
    float* __restrict__ outf,
    unsigned short* __restrict__ outb, size_t ostride,
    const float* __restrict__ resid,
    int Kd)
{
    __shared__ __align__(16) unsigned short As[128 * 32];
    __shared__ __align__(16) unsigned short Bs[128 * 32];
    const int tid = threadIdx.x;
    const int lane = tid & 63, wv = tid >> 6;
    const int wr = wv >> 1, wc = wv & 1;
    const int lm = lane & 15, lh = lane >> 4;
    const int m0 = blockIdx.y * 128, n0 = blockIdx.x * 128;
    const int z = blockIdx.z;
    const unsigned short* Wt = Wt0 + (size_t)z * wstride;
    const float* bias = (z == 0) ? bias0 : (z == 1) ? bias1 : bias2;

    f32x4 acc[4][4] = {};

    const int o0 = tid * 16;
    const int row0 = o0 >> 6, col0 = (o0 & 63) >> 1;
    const int row1 = row0 + 64;

    for (int k0 = 0; k0 < Kd; k0 += 32) {
        __syncthreads();
        gl_lds16(A  + (size_t)(m0 + row0) * Kd + k0 + col0, As + (o0 >> 1));
        gl_lds16(A  + (size_t)(m0 + row1) * Kd + k0 + col0, As + 2048 + (o0 >> 1));
        gl_lds16(Wt + (size_t)(n0 + row0) * Kd + k0 + col0, Bs + (o0 >> 1));
        gl_lds16(Wt + (size_t)(n0 + row1) * Kd + k0 + col0, Bs + 2048 + (o0 >> 1));
        __syncthreads();

        bf16x8 af[4], bfg[4];
#pragma unroll
        for (int mi = 0; mi < 4; mi++)
            af[mi] = *reinterpret_cast<const bf16x8*>(&As[(wr * 64 + mi * 16 + lm) * 32 + lh * 8]);
#pragma unroll
        for (int nj = 0; nj < 4; nj++)
            bfg[nj] = *reinterpret_cast<const bf16x8*>(&Bs[(wc * 64 + nj * 16 + lm) * 32 + lh * 8]);
        __builtin_amdgcn_s_setprio(1);
#pragma unroll
        for (int mi = 0; mi < 4; mi++)
#pragma unroll
            for (int nj = 0; nj < 4; nj++)
                acc[mi][nj] = __builtin_amdgcn_mfma_f32_16x16x32_bf16(af[mi], bfg[nj], acc[mi][nj], 0, 0, 0);
        __builtin_amdgcn_s_setprio(0);
    }

#pragma unroll
    for (int mi = 0; mi < 4; mi++) {
#pragma unroll
        for (int nj = 0; nj < 4; nj++) {
#pragma unroll
            for (int r = 0; r < 4; r++) {
                int i = m0 + wr * 64 + mi * 16 + lh * 4 + r;
                int j = n0 + wc * 64 + nj * 16 + lm;
                float val = acc[mi][nj][r] + bias[j];
                size_t oidx = (size_t)i * DD + j;
                if (resid) val += resid[oidx];
                if (outf) outf[oidx] = val;
                if (outb) outb[(size_t)z * ostride + oidx] = f2b(val);
            }
        }
    }
}

// ---------------- V transpose+convert: vb (B*N,D) bf16 -> vt (B,H,HD,N) F16 ----------
__global__ __launch_bounds__(256) void k_transpose_v(const unsigned short* __restrict__ vb,
                                                     unsigned short* __restrict__ vt) {
    __shared__ unsigned short tl[64 * 72];
    const int bh = blockIdx.x;
    const int b = bh >> 3, h = bh & 7;
    const int n0 = blockIdx.y * 64;
    const int t = threadIdx.x;
    {
        int n = t >> 2, seg = t & 3;
        const unsigned short* src = vb + ((size_t)b * NN + n0 + n) * DD + h * HDIM + seg * 16;
        int4 c0 = *reinterpret_cast<const int4*>(src);
        int4 c1 = *reinterpret_cast<const int4*>(src + 8);
        *reinterpret_cast<int4*>(&tl[n * 72 + seg * 16]) = c0;
        *reinterpret_cast<int4*>(&tl[n * 72 + seg * 16 + 8]) = c1;
    }
    __syncthreads();
    {
        int d = t & 63, nb = t >> 6;
        union { unsigned short s[8]; int4 v; } pk0, pk1;
#pragma unroll
        for (int q = 0; q < 8; q++) pk0.s[q] = h_bits((_Float16)b2f(tl[(nb * 16 + q) * 72 + d]));
#pragma unroll
        for (int q = 0; q < 8; q++) pk1.s[q] = h_bits((_Float16)b2f(tl[(nb * 16 + 8 + q) * 72 + d]));
        unsigned short* dst = vt + (((size_t)b * HH + h) * HDIM + d) * NN + n0 + nb * 16;
        *reinterpret_cast<int4*>(dst) = pk0.v;
        *reinterpret_cast<int4*>(dst + 8) = pk1.v;
    }
}

// ---------------- fused attention G=2 (R11 config): 32 q-rows/block, 2 chains/wave ---
// Grid 512 linear: xcd=lin&7, s=lin>>3, combo=xcd*2+(s>>5) = js*4+b, itg=s&31.
// Per j-iter: K,V loaded once, consumed by TWO independent QK/softmax/PV chains
// (g = 0,1 -> i-tiles itg*2, itg*2+1). E tiles (2 x 8 KB) DMA'd double-buffered.
template <int JS>
__global__ __launch_bounds__(512) void k_attn_g2(
    const unsigned short* __restrict__ qb,
    const unsigned short* __restrict__ kb,
    const unsigned short* __restrict__ vt,
    const unsigned short* __restrict__ ebt,  // f16 tile-blocked
    const float* __restrict__ ew,            // (L,E,H)
    const float* __restrict__ ebias,         // (L,H)
    int layer,
    unsigned short* __restrict__ outpb,      // (JS,B,N,D) bf16 partial O
    float2* __restrict__ mlp)                // (JS,B,H,N) partial (m,l)
{
    __shared__ __align__(16) unsigned short e_lds[2][2][4096];  // 32 KB
    __shared__ unsigned short p_lds[8][2][16 * 68];             // 34.8 KB
    const int lin = blockIdx.x;
    const int xcd = lin & 7;
    const int s   = lin >> 3;
    const int combo = xcd * 2 + (s >> 5);    // = js*4 + b
    const int itg = s & 31;
    const int b  = combo & 3;
    const int js = combo >> 2;
    const int tid = threadIdx.x;
    const int lane = tid & 63, wv = tid >> 6;
    const int h = wv;
    const int lm = lane & 15, lh = lane >> 4;

    const float LOG2E = 1.44269504f;
    const float ebh = ebias[layer * HH + h] * LOG2E;
    const float qscale = 0.125f * LOG2E;
    h2 w01, w23;
    w01.x = (_Float16)(ew[(layer * EE + 0) * HH + h] * LOG2E);
    w01.y = (_Float16)(ew[(layer * EE + 1) * HH + h] * LOG2E);
    w23.x = (_Float16)(ew[(layer * EE + 2) * HH + h] * LOG2E);
    w23.y = (_Float16)(ew[(layer * EE + 3) * HH + h] * LOG2E);

    bf16x8 aq[2][2];
#pragma unroll
    for (int g = 0; g < 2; g++) {
        const unsigned short* qrow =
            qb + ((size_t)(b * NN) + itg * 32 + g * 16 + lm) * DD + h * HDIM + lh * 8;
        aq[g][0] = *reinterpret_cast<const bf16x8*>(qrow);
        aq[g][1] = *reinterpret_cast<const bf16x8*>(qrow + 32);
    }

    f32x4 acc[2][4] = {};
    float m_run[2] = {-1e30f, -1e30f}, l_run[2] = {0.f, 0.f};

    constexpr int NITER = (NN / JS) / 64;
    const int jlo = js * (NN / JS);
    const int jb0 = jlo >> 6;
    const unsigned short* etile0 = ebt + ((size_t)((b * 64 + itg * 2 + 0) * 16 + jb0)) * 4096;
    const unsigned short* etile1 = ebt + ((size_t)((b * 64 + itg * 2 + 1) * 16 + jb0)) * 4096;
    const unsigned short* kptr = kb + ((size_t)(b * NN) + jlo + lm) * DD + h * HDIM + lh * 8;
    const unsigned short* vptr = vt + (((size_t)(b * HH) + h) * HDIM + lm) * NN + jlo + lh * 8;

    // prologue: DMA both g-tiles of j-tile 0
    gl_lds16(etile0 + tid * 8, &e_lds[0][0][tid * 8]);
    gl_lds16(etile1 + tid * 8, &e_lds[0][1][tid * 8]);
    __syncthreads();

#pragma unroll
    for (int i = 0; i < NITER; i++) {
        const int cur = i & 1;
        if (i + 1 < NITER) {
            gl_lds16(etile0 + (size_t)(i + 1) * 4096 + tid * 8, &e_lds[cur ^ 1][0][tid * 8]);
            gl_lds16(etile1 + (size_t)(i + 1) * 4096 + tid * 8, &e_lds[cur ^ 1][1][tid * 8]);
        }

        // ---- K and V for this j-tile (shared by both chains) ----
        bf16x8 kf[8];
        f16x8  vf[8];
#pragma unroll
        for (int jt = 0; jt < 4; jt++) {
            const unsigned short* kr = kptr + (size_t)i * 64 * DD + (size_t)jt * 16 * DD;
            kf[jt * 2]     = *reinterpret_cast<const bf16x8*>(kr);
            kf[jt * 2 + 1] = *reinterpret_cast<const bf16x8*>(kr + 32);
        }
#pragma unroll
        for (int kc = 0; kc < 2; kc++)
#pragma unroll
            for (int dt = 0; dt < 4; dt++)
                vf[kc * 4 + dt] = *reinterpret_cast<const f16x8*>(
                    vptr + (size_t)dt * 16 * NN + i * 64 + kc * 32);

        // ---- two independent chains ----
#pragma unroll
        for (int g = 0; g < 2; g++) {
            f32x4 sreg[4];
#pragma unroll
            for (int jt = 0; jt < 4; jt++) {
                f32x4 t = {};
                t = __builtin_amdgcn_mfma_f32_16x16x32_bf16(kf[jt * 2], aq[g][0], t, 0, 0, 0);
                t = __builtin_amdgcn_mfma_f32_16x16x32_bf16(kf[jt * 2 + 1], aq[g][1], t, 0, 0, 0);
                sreg[jt] = t;
            }

            float pv[16];
#pragma unroll
            for (int c = 0; c < 8; c++) {
                const uint4 ee = *reinterpret_cast<const uint4*>(
                    &e_lds[cur][g][(c * 64 + lane) * 8]);
                const int jt = c >> 1, r0 = (c & 1) * 2;
                pv[jt * 4 + r0] = fmaf(sreg[jt][r0], qscale,
                    __builtin_amdgcn_fdot2(u2h2(ee.x), w01,
                        __builtin_amdgcn_fdot2(u2h2(ee.y), w23, ebh, false), false));
                pv[jt * 4 + r0 + 1] = fmaf(sreg[jt][r0 + 1], qscale,
                    __builtin_amdgcn_fdot2(u2h2(ee.z), w01,
                        __builtin_amdgcn_fdot2(u2h2(ee.w), w23, ebh, false), false));
            }

            float mt = pv[0];
#pragma unroll
            for (int q = 1; q < 16; q++) mt = fmaxf(mt, pv[q]);
            mt = fmaxf(mt, __shfl_xor(mt, 16));
            mt = fmaxf(mt, __shfl_xor(mt, 32));
            float mn = fmaxf(m_run[g], mt);
            float corr = __builtin_amdgcn_exp2f(m_run[g] - mn);
            m_run[g] = mn;
            float ls = 0.f;
#pragma unroll
            for (int q = 0; q < 16; q++) {
                pv[q] = __builtin_amdgcn_exp2f(pv[q] - mn);
                ls += pv[q];
            }
            ls += __shfl_xor(ls, 16);
            ls += __shfl_xor(ls, 32);
            l_run[g] = l_run[g] * corr + ls;

#pragma unroll
            for (int jt = 0; jt < 4; jt++) {
                uint2 u;
                u.x = pkrtz_u32(pv[jt * 4 + 0], pv[jt * 4 + 1]);
                u.y = pkrtz_u32(pv[jt * 4 + 2], pv[jt * 4 + 3]);
                *reinterpret_cast<uint2*>(&p_lds[wv][g][lm * 68 + jt * 16 + lh * 4]) = u;
            }
#pragma unroll
            for (int dt = 0; dt < 4; dt++)
#pragma unroll
                for (int r = 0; r < 4; r++) acc[g][dt][r] *= corr;

#pragma unroll
            for (int kc = 0; kc < 2; kc++) {
                f16x8 pb = *reinterpret_cast<const f16x8*>(
                    &p_lds[wv][g][lm * 68 + kc * 32 + lh * 8]);
#pragma unroll
                for (int dt = 0; dt < 4; dt++)
                    acc[g][dt] = __builtin_amdgcn_mfma_f32_16x16x32_f16(
                        vf[kc * 4 + dt], pb, acc[g][dt], 0, 0, 0);
            }
        }

        __syncthreads();
    }

#pragma unroll
    for (int g = 0; g < 2; g++) {
        const int irow = itg * 32 + g * 16 + lm;
#pragma unroll
        for (int dt = 0; dt < 4; dt++) {
            union { unsigned short us[4]; uint2 u; } pk;
#pragma unroll
            for (int r = 0; r < 4; r++) pk.us[r] = f2b(acc[g][dt][r]);
            *reinterpret_cast<uint2*>(
                &outpb[((size_t)(js * BB + b) * NN + irow) * DD + h * HDIM + dt * 16 + lh * 4]) = pk.u;
        }
        if (lh == 0)
            mlp[((size_t)(js * BB + b) * HH + h) * NN + irow] = make_float2(m_run[g], l_run[g]);
    }
}

// ---------------- fallback fused attention (fp32 edges, unpipelined) ------------------
__global__ __launch_bounds__(512) void k_attn_f(
    const unsigned short* __restrict__ qb,
    const unsigned short* __restrict__ kb,
    const unsigned short* __restrict__ vt,
    const float* __restrict__ edges,
    const float* __restrict__ ew, const float* __restrict__ ebias,
    int layer,
    unsigned short* __restrict__ attnob)
{
    __shared__ unsigned short p_lds[8][16 * 68];
    const int b = blockIdx.y;
    const int i0 = blockIdx.x * 16;
    const int tid = threadIdx.x;
    const int lane = tid & 63, wv = tid >> 6;
    const int h = wv;
    const int lm = lane & 15, lh = lane >> 4;

    const float LOG2E = 1.44269504f;
    const float ew0 = ew[(layer * EE + 0) * HH + h] * LOG2E;
    const float ew1 = ew[(layer * EE + 1) * HH + h] * LOG2E;
    const float ew2 = ew[(layer * EE + 2) * HH + h] * LOG2E;
    const float ew3 = ew[(layer * EE + 3) * HH + h] * LOG2E;
    const float ebh = ebias[layer * HH + h] * LOG2E;
    const float qscale = 0.125f * LOG2E;

    const unsigned short* qrow = qb + ((size_t)(b * NN) + i0 + lm) * DD + h * HDIM + lh * 8;
    const bf16x8 aq0 = *reinterpret_cast<const bf16x8*>(qrow);
    const bf16x8 aq1 = *reinterpret_cast<const bf16x8*>(qrow + 32);

    f32x4 acc[4] = {};
    float m_run = -1e30f, l_run = 0.f;
    const float4* ef4 = (const float4*)edges;
    const size_t erowbase = ((size_t)b * NN + i0 + lm) * NN;

    for (int j0 = 0; j0 < NN; j0 += 64) {
        f32x4 sreg[4];
#pragma unroll
        for (int jt = 0; jt < 4; jt++) {
            const unsigned short* krow =
                kb + ((size_t)(b * NN) + j0 + jt * 16 + lm) * DD + h * HDIM + lh * 8;
            bf16x8 k0 = *reinterpret_cast<const bf16x8*>(krow);
            bf16x8 k1 = *reinterpret_cast<const bf16x8*>(krow + 32);
            f32x4 t = {};
            t = __builtin_amdgcn_mfma_f32_16x16x32_bf16(k0, aq0, t, 0, 0, 0);
            t = __builtin_amdgcn_mfma_f32_16x16x32_bf16(k1, aq1, t, 0, 0, 0);
            sreg[jt] = t;
        }
        float pv[16];
#pragma unroll
        for (int jt = 0; jt < 4; jt++) {
            const size_t jbase = erowbase + j0 + jt * 16 + lh * 4;
#pragma unroll
            for (int r = 0; r < 4; r++) {
                float4 e = ef4[jbase + r];
                pv[jt * 4 + r] = sreg[jt][r] * qscale
                    + e.x * ew0 + e.y * ew1 + e.z * ew2 + e.w * ew3 + ebh;
            }
        }
        float mt = pv[0];
#pragma unroll
        for (int q = 1; q < 16; q++) mt = fmaxf(mt, pv[q]);
        mt = fmaxf(mt, __shfl_xor(mt, 16));
        mt = fmaxf(mt, __shfl_xor(mt, 32));
        float mn = fmaxf(m_run, mt);
        float corr = __builtin_amdgcn_exp2f(m_run - mn);
        m_run = mn;
        float ls = 0.f;
#pragma unroll
        for (int q = 0; q < 16; q++) {
            pv[q] = __builtin_amdgcn_exp2f(pv[q] - mn);
            ls += pv[q];
        }
        ls += __shfl_xor(ls, 16);
        ls += __shfl_xor(ls, 32);
        l_run = l_run * corr + ls;
#pragma unroll
        for (int jt = 0; jt < 4; jt++) {
            uint2 u;
            u.x = pkrtz_u32(pv[jt * 4 + 0], pv[jt * 4 + 1]);
            u.y = pkrtz_u32(pv[jt * 4 + 2], pv[jt * 4 + 3]);
            *reinterpret_cast<uint2*>(&p_lds[wv][lm * 68 + jt * 16 + lh * 4]) = u;
        }
#pragma unroll
        for (int dt = 0; dt < 4; dt++)
#pragma unroll
            for (int r = 0; r < 4; r++) acc[dt][r] *= corr;
#pragma unroll
        for (int kc = 0; kc < 2; kc++) {
            f16x8 pb = *reinterpret_cast<const f16x8*>(&p_lds[wv][lm * 68 + kc * 32 + lh * 8]);
#pragma unroll
            for (int dt = 0; dt < 4; dt++) {
                f16x8 av = *reinterpret_cast<const f16x8*>(
                    vt + (((size_t)(b * HH) + h) * HDIM + dt * 16 + lm) * NN + j0 + kc * 32 + lh * 8);
                acc[dt] = __builtin_amdgcn_mfma_f32_16x16x32_f16(av, pb, acc[dt], 0, 0, 0);
            }
        }
    }
    const float inv = 1.f / l_run;
#pragma unroll
    for (int dt = 0; dt < 4; dt++) {
        union { unsigned short us[4]; uint2 u; } pk;
#pragma unroll
        for (int r = 0; r < 4; r++) pk.us[r] = f2b(acc[dt][r] * inv);
        *reinterpret_cast<uint2*>(
            &attnob[((size_t)(b * NN) + i0 + lm) * DD + h * HDIM + dt * 16 + lh * 4]) = pk.u;
    }
}

// ---------------- split-j reduce: combine JS bf16 partials -> bf16 attnob -------------
template <int JS>
__global__ __launch_bounds__(256) void k_attnred(
    const unsigned short* __restrict__ outpb, const float2* __restrict__ mlp,
    unsigned short* __restrict__ attnob)
{
    const int tid = blockIdx.x * 256 + threadIdx.x;   // (b,n,h,dc) dc = d/4
    const int dc = tid & 15;
    const int h = (tid >> 4) & 7;
    const int n = (tid >> 7) & (NN - 1);
    const int b = tid >> 17;
    float ms[JS], lsv[JS];
    float mstar = -1e30f;
#pragma unroll
    for (int s2 = 0; s2 < JS; s2++) {
        float2 ml = mlp[((size_t)(s2 * BB + b) * HH + h) * NN + n];
        ms[s2] = ml.x; lsv[s2] = ml.y;
        mstar = fmaxf(mstar, ml.x);
    }
    float lstar = 0.f;
    float o0 = 0.f, o1 = 0.f, o2 = 0.f, o3 = 0.f;
#pragma unroll
    for (int s2 = 0; s2 < JS; s2++) {
        float w = __builtin_amdgcn_exp2f(ms[s2] - mstar);
        lstar += w * lsv[s2];
        uint2 a = *reinterpret_cast<const uint2*>(
            &outpb[((size_t)(s2 * BB + b) * NN + n) * DD + h * HDIM + dc * 4]);
        o0 += w * b2f(a.x & 0xffffu); o1 += w * b2f(a.x >> 16);
        o2 += w * b2f(a.y & 0xffffu); o3 += w * b2f(a.y >> 16);
    }
    const float inv = 1.f / lstar;
    union { unsigned short us[4]; uint2 u; } pk;
    pk.us[0] = f2b(o0 * inv); pk.us[1] = f2b(o1 * inv);
    pk.us[2] = f2b(o2 * inv); pk.us[3] = f2b(o3 * inv);
    *reinterpret_cast<uint2*>(&attnob[((size_t)b * NN + n) * DD + h * HDIM + dc * 4]) = pk.u;
}

// ---------------- final layernorm: one wave per row ----------------
__global__ __launch_bounds__(64) void k_ln(const float* __restrict__ hbuf,
                                           const float* __restrict__ g,
                                           const float* __restrict__ bta,
                                           float* __restrict__ out) {
    const int row = blockIdx.x;
    const int lane = threadIdx.x;
    const float* hr = hbuf + (size_t)row * DD;
    float4 v0 = reinterpret_cast<const float4*>(hr)[lane * 2];
    float4 v1 = reinterpret_cast<const float4*>(hr)[lane * 2 + 1];
    float vals[8] = {v0.x, v0.y, v0.z, v0.w, v1.x, v1.y, v1.z, v1.w};
    float sum = 0.f, sq = 0.f;
#pragma unroll
    for (int q = 0; q < 8; q++) { sum += vals[q]; sq += vals[q] * vals[q]; }
#pragma unroll
    for (int m = 1; m <= 32; m <<= 1) {
        sum += __shfl_xor(sum, m);
        sq += __shfl_xor(sq, m);
    }
    float mu = sum * (1.f / DD);
    float var = sq * (1.f / DD) - mu * mu;
    float rs = rsqrtf(var + 1e-5f);
    const float* gp = g + lane * 8;
    const float* bp = bta + lane * 8;
    float* op = out + (size_t)row * DD + lane * 8;
#pragma unroll
    for (int q = 0; q < 8; q++) op[q] = (vals[q] - mu) * rs * gp[q] + bp[q];
}

extern "C" void kernel_launch(void* const* d_in, const int* in_sizes, int n_in,
                              void* d_out, int out_size, void* d_ws, size_t ws_size,
                              hipStream_t stream) {
    (void)in_sizes; (void)n_in; (void)out_size;
    const float* x     = (const float*)d_in[0];
    const float* edges = (const float*)d_in[1];
    const float* in_w  = (const float*)d_in[2];
    const float* in_b  = (const float*)d_in[3];
    const float* qw    = (const float*)d_in[4];
    const float* qbias = (const float*)d_in[5];
    const float* kw    = (const float*)d_in[6];
    const float* kbias = (const float*)d_in[7];
    const float* vw    = (const float*)d_in[8];
    const float* vbias = (const float*)d_in[9];
    const float* ow    = (const float*)d_in[10];
    const float* obias = (const float*)d_in[11];
    const float* ew    = (const float*)d_in[12];
    const float* ebias = (const float*)d_in[13];
    const float* ln_g  = (const float*)d_in[14];
    const float* ln_b  = (const float*)d_in[15];
    float* out = (float*)d_out;

    constexpr int JS = 4;
    char* ws = (char*)d_ws;
    size_t off = 0;
    auto alloc = [&](size_t bytes) -> void* {
        void* p = ws + off;
        off += (bytes + 255) & ~(size_t)255;
        return p;
    };
    const size_t M = (size_t)BB * NN;            // 4096
    float*          hbuf  = (float*)         alloc(M * DD * 4);
    unsigned short* hb    = (unsigned short*)alloc(M * DD * 2);
    unsigned short* xb    = (unsigned short*)alloc(M * INDIM * 2);
    unsigned short* wt_in = (unsigned short*)alloc((size_t)DD * INDIM * 2);
    unsigned short* wt    = (unsigned short*)alloc((size_t)12 * DD * DD * 2);
    unsigned short* qkvb  = (unsigned short*)alloc((size_t)3 * M * DD * 2);
    unsigned short* vtb   = (unsigned short*)alloc(M * DD * 2);
    unsigned short* attnob= (unsigned short*)alloc(M * DD * 2);
    const size_t edgeElems = (size_t)BB * NN * NN * EE;            // 16.8M
    unsigned short* ebt   = (unsigned short*)alloc(edgeElems * 2); // 33.5 MB tile-blocked f16
    const bool use_ebf = (off <= ws_size);
    unsigned short* outpb = (unsigned short*)alloc((size_t)JS * M * DD * 2);   // 16.8 MB
    float2*         mlp   = (float2*)        alloc((size_t)JS * BB * HH * NN * 8);
    const bool use_split = (off <= ws_size);
    const size_t BND = M * DD;

    // weight prep + input/edge conversion
    k_transpose_in<<<dim3(DD / 32, INDIM / 32), dim3(32, 8), 0, stream>>>(in_w, wt_in);
    k_transpose_qkvo<<<dim3(DD / 32, DD / 32, 12), dim3(32, 8), 0, stream>>>(qw, kw, vw, ow, wt);
    k_convert<<<dim3(512), dim3(256), 0, stream>>>(x, xb, (long long)(M * INDIM / 4));
    if (use_ebf && use_split)
        k_convert_e2<<<dim3(4096), dim3(256), 0, stream>>>(edges, ebt);

    // input projection: h = x @ in_w + in_b  (writes fp32 h and bf16 hb)
    k_gemm<<<dim3(4, 32, 1), dim3(256), 0, stream>>>(
        xb, wt_in, (size_t)0, in_b, in_b, in_b, hbuf, hb, (size_t)0, (const float*)nullptr, INDIM);

    for (int l = 0; l < LL; l++) {
        k_gemm<<<dim3(4, 32, 3), dim3(256), 0, stream>>>(
            hb, wt + (size_t)(l * 4) * DD * DD, (size_t)DD * DD,
            qbias + l * DD, kbias + l * DD, vbias + l * DD,
            (float*)nullptr, qkvb, BND, (const float*)nullptr, DD);
        k_transpose_v<<<dim3(32, 16), dim3(256), 0, stream>>>(qkvb + 2 * BND, vtb);

        if (use_ebf && use_split) {
            k_attn_g2<JS><<<dim3(512), dim3(512), 0, stream>>>(
                qkvb, qkvb + BND, vtb, ebt, ew, ebias, l, outpb, mlp);
            k_attnred<JS><<<dim3((unsigned)(M * HH * 16 / 256)), dim3(256), 0, stream>>>(
                outpb, mlp, attnob);
        } else {
            k_attn_f<<<dim3(64, BB, 1), dim3(512), 0, stream>>>(
                qkvb, qkvb + BND, vtb, edges, ew, ebias, l, attnob);
        }

        k_gemm<<<dim3(4, 32, 1), dim3(256), 0, stream>>>(
            attnob, wt + (size_t)(l * 4 + 3) * DD * DD, (size_t)0,
            obias + l * DD, obias + l * DD, obias + l * DD,
            hbuf, hb, (size_t)0, hbuf, DD);
    }

    k_ln<<<dim3((unsigned)M), dim3(64), 0, stream>>>(hbuf, ln_g, ln_b, out);
}

// Round 16
// 312.049 us; speedup vs baseline: 1.1989x; 1.1261x over previous
//
#include <hip/hip_runtime.h>
#include <hip/hip_bf16.h>
#include <cstdint>
#include <cstddef>

#define BB 4
#define NN 1024
#define INDIM 128
#define DD 512
#define HH 8
#define EE 4
#define LL 3
#define HDIM 64

typedef __bf16 bf16x8 __attribute__((ext_vector_type(8)));
typedef _Float16 f16x8 __attribute__((ext_vector_type(8)));
typedef _Float16 h2 __attribute__((ext_vector_type(2)));
typedef float f32x4 __attribute__((ext_vector_type(4)));
typedef unsigned int u32x4 __attribute__((ext_vector_type(4)));

__device__ __forceinline__ unsigned short f2b(float f) {
    union { float f; unsigned int u; } v; v.f = f;
    unsigned int u = v.u;
    unsigned int r = (u + 0x7FFFu + ((u >> 16) & 1u)) >> 16;
    return (unsigned short)r;
}
__device__ __forceinline__ float b2f(unsigned int us) {
    union { unsigned int u; float f; } v; v.u = us << 16; return v.f;
}
__device__ __forceinline__ unsigned short h_bits(_Float16 h) {
    union { _Float16 h; unsigned short u; } v; v.h = h; return v.u;
}
__device__ __forceinline__ h2 u2h2(unsigned int u) {
    union { unsigned int u; h2 h; } v; v.u = u; return v.h;
}
__device__ __forceinline__ unsigned int pkrtz_u32(float a, float b) {
    auto h = __builtin_amdgcn_cvt_pkrtz(a, b);
    union { decltype(h) h; unsigned int u; } v; v.h = h; return v.u;
}

__device__ __forceinline__ void gl_lds16(const unsigned short* g, unsigned short* l) {
    __builtin_amdgcn_global_load_lds(
        (const __attribute__((address_space(1))) void*)g,
        (__attribute__((address_space(3))) void*)l, 16, 0, 0);
}

// ---------------- weight transpose+convert: W (K x N fp32) -> Wt (N x K bf16) ---------
__device__ __forceinline__ void transpose_tile_body(const float* __restrict__ src,
                                                    unsigned short* __restrict__ dst,
                                                    int K, int Nc) {
    __shared__ float tl[32][33];
    const int n0 = blockIdx.x * 32, k0 = blockIdx.y * 32;
    const int tx = threadIdx.x, ty = threadIdx.y;
#pragma unroll
    for (int r = 0; r < 4; r++) {
        int k = ty + r * 8;
        tl[k][tx] = src[(size_t)(k0 + k) * Nc + n0 + tx];
    }
    __syncthreads();
#pragma unroll
    for (int r = 0; r < 4; r++) {
        int n = ty + r * 8;
        dst[(size_t)(n0 + n) * K + k0 + tx] = f2b(tl[tx][n]);
    }
}

__global__ void k_transpose_in(const float* __restrict__ w, unsigned short* __restrict__ dst) {
    transpose_tile_body(w, dst, INDIM, DD);
}

__global__ void k_transpose_qkvo(const float* __restrict__ qw, const float* __restrict__ kw,
                                 const float* __restrict__ vw, const float* __restrict__ ow,
                                 unsigned short* __restrict__ dst) {
    int zz = blockIdx.z;
    int l = zz >> 2, tsel = zz & 3;
    const float* src = (tsel == 0) ? qw : (tsel == 1) ? kw : (tsel == 2) ? vw : ow;
    src += (size_t)l * DD * DD;
    transpose_tile_body(src, dst + (size_t)zz * DD * DD, DD, DD);
}

// ---------------- fp32 -> bf16 convert (x) ----------------
__global__ void k_convert(const float* __restrict__ src, unsigned short* __restrict__ dst,
                          long long n4) {
    long long stride = (long long)gridDim.x * blockDim.x;
    for (long long i = blockIdx.x * (long long)blockDim.x + threadIdx.x; i < n4; i += stride) {
        float4 v = reinterpret_cast<const float4*>(src)[i];
        uint2 o;
        o.x = (unsigned)f2b(v.x) | ((unsigned)f2b(v.y) << 16);
        o.y = (unsigned)f2b(v.z) | ((unsigned)f2b(v.w) << 16);
        reinterpret_cast<uint2*>(dst)[i] = o;
    }
}

// ---------------- edges fp32 -> tile-blocked F16 layout (ebt2) ----------------
// Tile = (b, it, jb): 8 KB of 16i x 64j x 4e f16; attn slot (c, lane) holds the quad
// for i = it*16 + (lane&15), j = jb*64 + (c>>1)*16 + (lane>>4)*4 + (c&1)*2 + q.
__global__ __launch_bounds__(256) void k_convert_e2(const float* __restrict__ src,
                                                    unsigned short* __restrict__ dst) {
    __shared__ unsigned short tl[4096];   // 8 KB tile
    const int tile = blockIdx.x;          // (b*64 + it)*16 + jb
    const int jb = tile & 15;
    const int it = (tile >> 4) & 63;
    const int b  = tile >> 10;
    const int tid = threadIdx.x;
    const int f4 = tid & 63;              // j_off within tile
    const int r0 = tid >> 6;              // 0..3
    const int jt = f4 >> 4, w16 = f4 & 15;
    const int lh = w16 >> 2, rr = w16 & 3;
    const int c = jt * 2 + (rr >> 1), q = rr & 1;
#pragma unroll
    for (int rd = 0; rd < 4; rd++) {
        const int lm = rd * 4 + r0;       // i within tile
        const float4 e = *reinterpret_cast<const float4*>(
            &src[(((size_t)b * NN + it * 16 + lm) * NN + jb * 64 + f4) * EE]);
        uint2 o;
        o.x = pkrtz_u32(e.x, e.y);
        o.y = pkrtz_u32(e.z, e.w);
        const int slot = c * 128 + (lh * 16 + lm) * 2 + q;   // uint2 units
        *reinterpret_cast<uint2*>(&tl[slot * 4]) = o;
    }
    __syncthreads();
    u32x4* g = reinterpret_cast<u32x4*>(dst) + (size_t)tile * 512;
    const u32x4* s = reinterpret_cast<const u32x4*>(tl);
    __builtin_nontemporal_store(s[tid], g + tid);
    __builtin_nontemporal_store(s[tid + 256], g + tid + 256);
}

// ---------------- bf16 MFMA GEMM: 128x64 tile, global_load_lds, m97 staging ----------
// 4 waves in 2x2 grid; each wave computes 64x32 via 4x2 fragments of 16x16x32.
// Grids chosen so blocks/CU is integral (256 CUs): in/o-proj 256, qkv 768.
__global__ __launch_bounds__(256) void k_gemm(
    const unsigned short* __restrict__ A,
    const unsigned short* __restrict__ Wt0, size_t wstride,
    const float* __restrict__ bias0, const float* __restrict__ bias1, const float* __restrict__ bias2,
    float* __restrict__ outf,
    unsigned short* __restrict__ outb, size_t ostride,
    const float* __restrict__ resid,
    int Kd)
{
    __shared__ __align__(16) unsigned short As[128 * 32];
    __shared__ __align__(16) unsigned short Bs[64 * 32];
    const int tid = threadIdx.x;
    const int lane = tid & 63, wv = tid >> 6;
    const int wr = wv >> 1, wc = wv & 1;
    const int lm = lane & 15, lh = lane >> 4;
    const int m0 = blockIdx.y * 128, n0 = blockIdx.x * 64;
    const int z = blockIdx.z;
    const unsigned short* Wt = Wt0 + (size_t)z * wstride;
    const float* bias = (z == 0) ? bias0 : (z == 1) ? bias1 : bias2;

    f32x4 acc[4][2] = {};

    const int o0 = tid * 16;
    const int rowA = o0 >> 6, colA = (o0 & 63) >> 1;
    for (int k0 = 0; k0 < Kd; k0 += 32) {
        __syncthreads();
        gl_lds16(A  + (size_t)(m0 + rowA) * Kd + k0 + colA, As + (o0 >> 1));
        gl_lds16(A  + (size_t)(m0 + 64 + rowA) * Kd + k0 + colA, As + 2048 + (o0 >> 1));
        gl_lds16(Wt + (size_t)(n0 + rowA) * Kd + k0 + colA, Bs + (o0 >> 1));
        __syncthreads();

        bf16x8 af[4], bfg[2];
#pragma unroll
        for (int mi = 0; mi < 4; mi++)
            af[mi] = *reinterpret_cast<const bf16x8*>(&As[(wr * 64 + mi * 16 + lm) * 32 + lh * 8]);
#pragma unroll
        for (int nj = 0; nj < 2; nj++)
            bfg[nj] = *reinterpret_cast<const bf16x8*>(&Bs[(wc * 32 + nj * 16 + lm) * 32 + lh * 8]);
        __builtin_amdgcn_s_setprio(1);
#pragma unroll
        for (int mi = 0; mi < 4; mi++)
#pragma unroll
            for (int nj = 0; nj < 2; nj++)
                acc[mi][nj] = __builtin_amdgcn_mfma_f32_16x16x32_bf16(af[mi], bfg[nj], acc[mi][nj], 0, 0, 0);
        __builtin_amdgcn_s_setprio(0);
    }

#pragma unroll
    for (int mi = 0; mi < 4; mi++) {
#pragma unroll
        for (int nj = 0; nj < 2; nj++) {
#pragma unroll
            for (int r = 0; r < 4; r++) {
                int i = m0 + wr * 64 + mi * 16 + lh * 4 + r;
                int j = n0 + wc * 32 + nj * 16 + lm;
                float val = acc[mi][nj][r] + bias[j];
                size_t oidx = (size_t)i * DD + j;
                if (resid) val += resid[oidx];
                if (outf) outf[oidx] = val;
                if (outb) outb[(size_t)z * ostride + oidx] = f2b(val);
            }
        }
    }
}

// ---------------- V transpose+convert: vb (B*N,D) bf16 -> vt (B,H,HD,N) F16 ----------
__global__ __launch_bounds__(256) void k_transpose_v(const unsigned short* __restrict__ vb,
                                                     unsigned short* __restrict__ vt) {
    __shared__ unsigned short tl[64 * 72];
    const int bh = blockIdx.x;
    const int b = bh >> 3, h = bh & 7;
    const int n0 = blockIdx.y * 64;
    const int t = threadIdx.x;
    {
        int n = t >> 2, seg = t & 3;
        const unsigned short* src = vb + ((size_t)b * NN + n0 + n) * DD + h * HDIM + seg * 16;
        int4 c0 = *reinterpret_cast<const int4*>(src);
        int4 c1 = *reinterpret_cast<const int4*>(src + 8);
        *reinterpret_cast<int4*>(&tl[n * 72 + seg * 16]) = c0;
        *reinterpret_cast<int4*>(&tl[n * 72 + seg * 16 + 8]) = c1;
    }
    __syncthreads();
    {
        int d = t & 63, nb = t >> 6;
        union { unsigned short s[8]; int4 v; } pk0, pk1;
#pragma unroll
        for (int q = 0; q < 8; q++) pk0.s[q] = h_bits((_Float16)b2f(tl[(nb * 16 + q) * 72 + d]));
#pragma unroll
        for (int q = 0; q < 8; q++) pk1.s[q] = h_bits((_Float16)b2f(tl[(nb * 16 + 8 + q) * 72 + d]));
        unsigned short* dst = vt + (((size_t)b * HH + h) * HDIM + d) * NN + n0 + nb * 16;
        *reinterpret_cast<int4*>(dst) = pk0.v;
        *reinterpret_cast<int4*>(dst + 8) = pk1.v;
    }
}

// ---------------- fused attention G=2 (R11/R15 config): 32 q-rows/block --------------
// Grid 512 linear: xcd=lin&7, s=lin>>3, combo=xcd*2+(s>>5) = js*4+b, itg=s&31.
// Per j-iter: K,V loaded once, consumed by TWO independent QK/softmax/PV chains
// (g = 0,1 -> i-tiles itg*2, itg*2+1). E tiles (2 x 8 KB) DMA'd double-buffered.
template <int JS>
__global__ __launch_bounds__(512) void k_attn_g2(
    const unsigned short* __restrict__ qb,
    const unsigned short* __restrict__ kb,
    const unsigned short* __restrict__ vt,
    const unsigned short* __restrict__ ebt,  // f16 tile-blocked
    const float* __restrict__ ew,            // (L,E,H)
    const float* __restrict__ ebias,         // (L,H)
    int layer,
    unsigned short* __restrict__ outpb,      // (JS,B,N,D) bf16 partial O
    float2* __restrict__ mlp)                // (JS,B,H,N) partial (m,l)
{
    __shared__ __align__(16) unsigned short e_lds[2][2][4096];  // 32 KB
    __shared__ unsigned short p_lds[8][2][16 * 68];             // 34.8 KB
    const int lin = blockIdx.x;
    const int xcd = lin & 7;
    const int s   = lin >> 3;
    const int combo = xcd * 2 + (s >> 5);    // = js*4 + b
    const int itg = s & 31;
    const int b  = combo & 3;
    const int js = combo >> 2;
    const int tid = threadIdx.x;
    const int lane = tid & 63, wv = tid >> 6;
    const int h = wv;
    const int lm = lane & 15, lh = lane >> 4;

    const float LOG2E = 1.44269504f;
    const float ebh = ebias[layer * HH + h] * LOG2E;
    const float qscale = 0.125f * LOG2E;
    h2 w01, w23;
    w01.x = (_Float16)(ew[(layer * EE + 0) * HH + h] * LOG2E);
    w01.y = (_Float16)(ew[(layer * EE + 1) * HH + h] * LOG2E);
    w23.x = (_Float16)(ew[(layer * EE + 2) * HH + h] * LOG2E);
    w23.y = (_Float16)(ew[(layer * EE + 3) * HH + h] * LOG2E);

    bf16x8 aq[2][2];
#pragma unroll
    for (int g = 0; g < 2; g++) {
        const unsigned short* qrow =
            qb + ((size_t)(b * NN) + itg * 32 + g * 16 + lm) * DD + h * HDIM + lh * 8;
        aq[g][0] = *reinterpret_cast<const bf16x8*>(qrow);
        aq[g][1] = *reinterpret_cast<const bf16x8*>(qrow + 32);
    }

    f32x4 acc[2][4] = {};
    float m_run[2] = {-1e30f, -1e30f}, l_run[2] = {0.f, 0.f};

    constexpr int NITER = (NN / JS) / 64;
    const int jlo = js * (NN / JS);
    const int jb0 = jlo >> 6;
    const unsigned short* etile0 = ebt + ((size_t)((b * 64 + itg * 2 + 0) * 16 + jb0)) * 4096;
    const unsigned short* etile1 = ebt + ((size_t)((b * 64 + itg * 2 + 1) * 16 + jb0)) * 4096;
    const unsigned short* kptr = kb + ((size_t)(b * NN) + jlo + lm) * DD + h * HDIM + lh * 8;
    const unsigned short* vptr = vt + (((size_t)(b * HH) + h) * HDIM + lm) * NN + jlo + lh * 8;

    // prologue: DMA both g-tiles of j-tile 0
    gl_lds16(etile0 + tid * 8, &e_lds[0][0][tid * 8]);
    gl_lds16(etile1 + tid * 8, &e_lds[0][1][tid * 8]);
    __syncthreads();

#pragma unroll
    for (int i = 0; i < NITER; i++) {
        const int cur = i & 1;
        if (i + 1 < NITER) {
            gl_lds16(etile0 + (size_t)(i + 1) * 4096 + tid * 8, &e_lds[cur ^ 1][0][tid * 8]);
            gl_lds16(etile1 + (size_t)(i + 1) * 4096 + tid * 8, &e_lds[cur ^ 1][1][tid * 8]);
        }

        // ---- K and V for this j-tile (shared by both chains) ----
        bf16x8 kf[8];
        f16x8  vf[8];
#pragma unroll
        for (int jt = 0; jt < 4; jt++) {
            const unsigned short* kr = kptr + (size_t)i * 64 * DD + (size_t)jt * 16 * DD;
            kf[jt * 2]     = *reinterpret_cast<const bf16x8*>(kr);
            kf[jt * 2 + 1] = *reinterpret_cast<const bf16x8*>(kr + 32);
        }
#pragma unroll
        for (int kc = 0; kc < 2; kc++)
#pragma unroll
            for (int dt = 0; dt < 4; dt++)
                vf[kc * 4 + dt] = *reinterpret_cast<const f16x8*>(
                    vptr + (size_t)dt * 16 * NN + i * 64 + kc * 32);

        // ---- two independent chains ----
#pragma unroll
        for (int g = 0; g < 2; g++) {
            f32x4 sreg[4];
#pragma unroll
            for (int jt = 0; jt < 4; jt++) {
                f32x4 t = {};
                t = __builtin_amdgcn_mfma_f32_16x16x32_bf16(kf[jt * 2], aq[g][0], t, 0, 0, 0);
                t = __builtin_amdgcn_mfma_f32_16x16x32_bf16(kf[jt * 2 + 1], aq[g][1], t, 0, 0, 0);
                sreg[jt] = t;
            }

            float pv[16];
#pragma unroll
            for (int c = 0; c < 8; c++) {
                const uint4 ee = *reinterpret_cast<const uint4*>(
                    &e_lds[cur][g][(c * 64 + lane) * 8]);
                const int jt = c >> 1, r0 = (c & 1) * 2;
                pv[jt * 4 + r0] = fmaf(sreg[jt][r0], qscale,
                    __builtin_amdgcn_fdot2(u2h2(ee.x), w01,
                        __builtin_amdgcn_fdot2(u2h2(ee.y), w23, ebh, false), false));
                pv[jt * 4 + r0 + 1] = fmaf(sreg[jt][r0 + 1], qscale,
                    __builtin_amdgcn_fdot2(u2h2(ee.z), w01,
                        __builtin_amdgcn_fdot2(u2h2(ee.w), w23, ebh, false), false));
            }

            float mt = pv[0];
#pragma unroll
            for (int q = 1; q < 16; q++) mt = fmaxf(mt, pv[q]);
            mt = fmaxf(mt, __shfl_xor(mt, 16));
            mt = fmaxf(mt, __shfl_xor(mt, 32));
            float mn = fmaxf(m_run[g], mt);
            float corr = __builtin_amdgcn_exp2f(m_run[g] - mn);
            m_run[g] = mn;
            float ls = 0.f;
#pragma unroll
            for (int q = 0; q < 16; q++) {
                pv[q] = __builtin_amdgcn_exp2f(pv[q] - mn);
                ls += pv[q];
            }
            ls += __shfl_xor(ls, 16);
            ls += __shfl_xor(ls, 32);
            l_run[g] = l_run[g] * corr + ls;

#pragma unroll
            for (int jt = 0; jt < 4; jt++) {
                uint2 u;
                u.x = pkrtz_u32(pv[jt * 4 + 0], pv[jt * 4 + 1]);
                u.y = pkrtz_u32(pv[jt * 4 + 2], pv[jt * 4 + 3]);
                *reinterpret_cast<uint2*>(&p_lds[wv][g][lm * 68 + jt * 16 + lh * 4]) = u;
            }
#pragma unroll
            for (int dt = 0; dt < 4; dt++)
#pragma unroll
                for (int r = 0; r < 4; r++) acc[g][dt][r] *= corr;

#pragma unroll
            for (int kc = 0; kc < 2; kc++) {
                f16x8 pb = *reinterpret_cast<const f16x8*>(
                    &p_lds[wv][g][lm * 68 + kc * 32 + lh * 8]);
#pragma unroll
                for (int dt = 0; dt < 4; dt++)
                    acc[g][dt] = __builtin_amdgcn_mfma_f32_16x16x32_f16(
                        vf[kc * 4 + dt], pb, acc[g][dt], 0, 0, 0);
            }
        }

        __syncthreads();
    }

#pragma unroll
    for (int g = 0; g < 2; g++) {
        const int irow = itg * 32 + g * 16 + lm;
#pragma unroll
        for (int dt = 0; dt < 4; dt++) {
            union { unsigned short us[4]; uint2 u; } pk;
#pragma unroll
            for (int r = 0; r < 4; r++) pk.us[r] = f2b(acc[g][dt][r]);
            *reinterpret_cast<uint2*>(
                &outpb[((size_t)(js * BB + b) * NN + irow) * DD + h * HDIM + dt * 16 + lh * 4]) = pk.u;
        }
        if (lh == 0)
            mlp[((size_t)(js * BB + b) * HH + h) * NN + irow] = make_float2(m_run[g], l_run[g]);
    }
}

// ---------------- fallback fused attention (fp32 edges, unpipelined) ------------------
__global__ __launch_bounds__(512) void k_attn_f(
    const unsigned short* __restrict__ qb,
    const unsigned short* __restrict__ kb,
    const unsigned short* __restrict__ vt,
    const float* __restrict__ edges,
    const float* __restrict__ ew, const float* __restrict__ ebias,
    int layer,
    unsigned short* __restrict__ attnob)
{
    __shared__ unsigned short p_lds[8][16 * 68];
    const int b = blockIdx.y;
    const int i0 = blockIdx.x * 16;
    const int tid = threadIdx.x;
    const int lane = tid & 63, wv = tid >> 6;
    const int h = wv;
    const int lm = lane & 15, lh = lane >> 4;

    const float LOG2E = 1.44269504f;
    const float ew0 = ew[(layer * EE + 0) * HH + h] * LOG2E;
    const float ew1 = ew[(layer * EE + 1) * HH + h] * LOG2E;
    const float ew2 = ew[(layer * EE + 2) * HH + h] * LOG2E;
    const float ew3 = ew[(layer * EE + 3) * HH + h] * LOG2E;
    const float ebh = ebias[layer * HH + h] * LOG2E;
    const float qscale = 0.125f * LOG2E;

    const unsigned short* qrow = qb + ((size_t)(b * NN) + i0 + lm) * DD + h * HDIM + lh * 8;
    const bf16x8 aq0 = *reinterpret_cast<const bf16x8*>(qrow);
    const bf16x8 aq1 = *reinterpret_cast<const bf16x8*>(qrow + 32);

    f32x4 acc[4] = {};
    float m_run = -1e30f, l_run = 0.f;
    const float4* ef4 = (const float4*)edges;
    const size_t erowbase = ((size_t)b * NN + i0 + lm) * NN;

    for (int j0 = 0; j0 < NN; j0 += 64) {
        f32x4 sreg[4];
#pragma unroll
        for (int jt = 0; jt < 4; jt++) {
            const unsigned short* krow =
                kb + ((size_t)(b * NN) + j0 + jt * 16 + lm) * DD + h * HDIM + lh * 8;
            bf16x8 k0 = *reinterpret_cast<const bf16x8*>(krow);
            bf16x8 k1 = *reinterpret_cast<const bf16x8*>(krow + 32);
            f32x4 t = {};
            t = __builtin_amdgcn_mfma_f32_16x16x32_bf16(k0, aq0, t, 0, 0, 0);
            t = __builtin_amdgcn_mfma_f32_16x16x32_bf16(k1, aq1, t, 0, 0, 0);
            sreg[jt] = t;
        }
        float pv[16];
#pragma unroll
        for (int jt = 0; jt < 4; jt++) {
            const size_t jbase = erowbase + j0 + jt * 16 + lh * 4;
#pragma unroll
            for (int r = 0; r < 4; r++) {
                float4 e = ef4[jbase + r];
                pv[jt * 4 + r] = sreg[jt][r] * qscale
                    + e.x * ew0 + e.y * ew1 + e.z * ew2 + e.w * ew3 + ebh;
            }
        }
        float mt = pv[0];
#pragma unroll
        for (int q = 1; q < 16; q++) mt = fmaxf(mt, pv[q]);
        mt = fmaxf(mt, __shfl_xor(mt, 16));
        mt = fmaxf(mt, __shfl_xor(mt, 32));
        float mn = fmaxf(m_run, mt);
        float corr = __builtin_amdgcn_exp2f(m_run - mn);
        m_run = mn;
        float ls = 0.f;
#pragma unroll
        for (int q = 0; q < 16; q++) {
            pv[q] = __builtin_amdgcn_exp2f(pv[q] - mn);
            ls += pv[q];
        }
        ls += __shfl_xor(ls, 16);
        ls += __shfl_xor(ls, 32);
        l_run = l_run * corr + ls;
#pragma unroll
        for (int jt = 0; jt < 4; jt++) {
            uint2 u;
            u.x = pkrtz_u32(pv[jt * 4 + 0], pv[jt * 4 + 1]);
            u.y = pkrtz_u32(pv[jt * 4 + 2], pv[jt * 4 + 3]);
            *reinterpret_cast<uint2*>(&p_lds[wv][lm * 68 + jt * 16 + lh * 4]) = u;
        }
#pragma unroll
        for (int dt = 0; dt < 4; dt++)
#pragma unroll
            for (int r = 0; r < 4; r++) acc[dt][r] *= corr;
#pragma unroll
        for (int kc = 0; kc < 2; kc++) {
            f16x8 pb = *reinterpret_cast<const f16x8*>(&p_lds[wv][lm * 68 + kc * 32 + lh * 8]);
#pragma unroll
            for (int dt = 0; dt < 4; dt++) {
                f16x8 av = *reinterpret_cast<const f16x8*>(
                    vt + (((size_t)(b * HH) + h) * HDIM + dt * 16 + lm) * NN + j0 + kc * 32 + lh * 8);
                acc[dt] = __builtin_amdgcn_mfma_f32_16x16x32_f16(av, pb, acc[dt], 0, 0, 0);
            }
        }
    }
    const float inv = 1.f / l_run;
#pragma unroll
    for (int dt = 0; dt < 4; dt++) {
        union { unsigned short us[4]; uint2 u; } pk;
#pragma unroll
        for (int r = 0; r < 4; r++) pk.us[r] = f2b(acc[dt][r] * inv);
        *reinterpret_cast<uint2*>(
            &attnob[((size_t)(b * NN) + i0 + lm) * DD + h * HDIM + dt * 16 + lh * 4]) = pk.u;
    }
}

// ---------------- split-j reduce: combine JS bf16 partials -> bf16 attnob -------------
template <int JS>
__global__ __launch_bounds__(256) void k_attnred(
    const unsigned short* __restrict__ outpb, const float2* __restrict__ mlp,
    unsigned short* __restrict__ attnob)
{
    const int tid = blockIdx.x * 256 + threadIdx.x;   // (b,n,h,dc) dc = d/4
    const int dc = tid & 15;
    const int h = (tid >> 4) & 7;
    const int n = (tid >> 7) & (NN - 1);
    const int b = tid >> 17;
    float ms[JS], lsv[JS];
    float mstar = -1e30f;
#pragma unroll
    for (int s2 = 0; s2 < JS; s2++) {
        float2 ml = mlp[((size_t)(s2 * BB + b) * HH + h) * NN + n];
        ms[s2] = ml.x; lsv[s2] = ml.y;
        mstar = fmaxf(mstar, ml.x);
    }
    float lstar = 0.f;
    float o0 = 0.f, o1 = 0.f, o2 = 0.f, o3 = 0.f;
#pragma unroll
    for (int s2 = 0; s2 < JS; s2++) {
        float w = __builtin_amdgcn_exp2f(ms[s2] - mstar);
        lstar += w * lsv[s2];
        uint2 a = *reinterpret_cast<const uint2*>(
            &outpb[((size_t)(s2 * BB + b) * NN + n) * DD + h * HDIM + dc * 4]);
        o0 += w * b2f(a.x & 0xffffu); o1 += w * b2f(a.x >> 16);
        o2 += w * b2f(a.y & 0xffffu); o3 += w * b2f(a.y >> 16);
    }
    const float inv = 1.f / lstar;
    union { unsigned short us[4]; uint2 u; } pk;
    pk.us[0] = f2b(o0 * inv); pk.us[1] = f2b(o1 * inv);
    pk.us[2] = f2b(o2 * inv); pk.us[3] = f2b(o3 * inv);
    *reinterpret_cast<uint2*>(&attnob[((size_t)b * NN + n) * DD + h * HDIM + dc * 4]) = pk.u;
}

// ---------------- final layernorm: one wave per row ----------------
__global__ __launch_bounds__(64) void k_ln(const float* __restrict__ hbuf,
                                           const float* __restrict__ g,
                                           const float* __restrict__ bta,
                                           float* __restrict__ out) {
    const int row = blockIdx.x;
    const int lane = threadIdx.x;
    const float* hr = hbuf + (size_t)row * DD;
    float4 v0 = reinterpret_cast<const float4*>(hr)[lane * 2];
    float4 v1 = reinterpret_cast<const float4*>(hr)[lane * 2 + 1];
    float vals[8] = {v0.x, v0.y, v0.z, v0.w, v1.x, v1.y, v1.z, v1.w};
    float sum = 0.f, sq = 0.f;
#pragma unroll
    for (int q = 0; q < 8; q++) { sum += vals[q]; sq += vals[q] * vals[q]; }
#pragma unroll
    for (int m = 1; m <= 32; m <<= 1) {
        sum += __shfl_xor(sum, m);
        sq += __shfl_xor(sq, m);
    }
    float mu = sum * (1.f / DD);
    float var = sq * (1.f / DD) - mu * mu;
    float rs = rsqrtf(var + 1e-5f);
    const float* gp = g + lane * 8;
    const float* bp = bta + lane * 8;
    float* op = out + (size_t)row * DD + lane * 8;
#pragma unroll
    for (int q = 0; q < 8; q++) op[q] = (vals[q] - mu) * rs * gp[q] + bp[q];
}

extern "C" void kernel_launch(void* const* d_in, const int* in_sizes, int n_in,
                              void* d_out, int out_size, void* d_ws, size_t ws_size,
                              hipStream_t stream) {
    (void)in_sizes; (void)n_in; (void)out_size;
    const float* x     = (const float*)d_in[0];
    const float* edges = (const float*)d_in[1];
    const float* in_w  = (const float*)d_in[2];
    const float* in_b  = (const float*)d_in[3];
    const float* qw    = (const float*)d_in[4];
    const float* qbias = (const float*)d_in[5];
    const float* kw    = (const float*)d_in[6];
    const float* kbias = (const float*)d_in[7];
    const float* vw    = (const float*)d_in[8];
    const float* vbias = (const float*)d_in[9];
    const float* ow    = (const float*)d_in[10];
    const float* obias = (const float*)d_in[11];
    const float* ew    = (const float*)d_in[12];
    const float* ebias = (const float*)d_in[13];
    const float* ln_g  = (const float*)d_in[14];
    const float* ln_b  = (const float*)d_in[15];
    float* out = (float*)d_out;

    constexpr int JS = 4;
    char* ws = (char*)d_ws;
    size_t off = 0;
    auto alloc = [&](size_t bytes) -> void* {
        void* p = ws + off;
        off += (bytes + 255) & ~(size_t)255;
        return p;
    };
    const size_t M = (size_t)BB * NN;            // 4096
    float*          hbuf  = (float*)         alloc(M * DD * 4);
    unsigned short* hb    = (unsigned short*)alloc(M * DD * 2);
    unsigned short* xb    = (unsigned short*)alloc(M * INDIM * 2);
    unsigned short* wt_in = (unsigned short*)alloc((size_t)DD * INDIM * 2);
    unsigned short* wt    = (unsigned short*)alloc((size_t)12 * DD * DD * 2);
    unsigned short* qkvb  = (unsigned short*)alloc((size_t)3 * M * DD * 2);
    unsigned short* vtb   = (unsigned short*)alloc(M * DD * 2);
    unsigned short* attnob= (unsigned short*)alloc(M * DD * 2);
    const size_t edgeElems = (size_t)BB * NN * NN * EE;            // 16.8M
    unsigned short* ebt   = (unsigned short*)alloc(edgeElems * 2); // 33.5 MB tile-blocked f16
    const bool use_ebf = (off <= ws_size);
    unsigned short* outpb = (unsigned short*)alloc((size_t)JS * M * DD * 2);   // 16.8 MB
    float2*         mlp   = (float2*)        alloc((size_t)JS * BB * HH * NN * 8);
    const bool use_split = (off <= ws_size);
    const size_t BND = M * DD;

    // weight prep + input/edge conversion
    k_transpose_in<<<dim3(DD / 32, INDIM / 32), dim3(32, 8), 0, stream>>>(in_w, wt_in);
    k_transpose_qkvo<<<dim3(DD / 32, DD / 32, 12), dim3(32, 8), 0, stream>>>(qw, kw, vw, ow, wt);
    k_convert<<<dim3(512), dim3(256), 0, stream>>>(x, xb, (long long)(M * INDIM / 4));
    if (use_ebf && use_split)
        k_convert_e2<<<dim3(4096), dim3(256), 0, stream>>>(edges, ebt);

    // input projection: h = x @ in_w + in_b  (writes fp32 h and bf16 hb)
    k_gemm<<<dim3(8, 32, 1), dim3(256), 0, stream>>>(
        xb, wt_in, (size_t)0, in_b, in_b, in_b, hbuf, hb, (size_t)0, (const float*)nullptr, INDIM);

    for (int l = 0; l < LL; l++) {
        k_gemm<<<dim3(8, 32, 3), dim3(256), 0, stream>>>(
            hb, wt + (size_t)(l * 4) * DD * DD, (size_t)DD * DD,
            qbias + l * DD, kbias + l * DD, vbias + l * DD,
            (float*)nullptr, qkvb, BND, (const float*)nullptr, DD);
        k_transpose_v<<<dim3(32, 16), dim3(256), 0, stream>>>(qkvb + 2 * BND, vtb);

        if (use_ebf && use_split) {
            k_attn_g2<JS><<<dim3(512), dim3(512), 0, stream>>>(
                qkvb, qkvb + BND, vtb, ebt, ew, ebias, l, outpb, mlp);
            k_attnred<JS><<<dim3((unsigned)(M * HH * 16 / 256)), dim3(256), 0, stream>>>(
                outpb, mlp, attnob);
        } else {
            k_attn_f<<<dim3(64, BB, 1), dim3(512), 0, stream>>>(
                qkvb, qkvb + BND, vtb, edges, ew, ebias, l, attnob);
        }

        k_gemm<<<dim3(8, 32, 1), dim3(256), 0, stream>>>(
            attnob, wt + (size_t)(l * 4 + 3) * DD * DD, (size_t)0,
            obias + l * DD, obias + l * DD, obias + l * DD,
            hbuf, hb, (size_t)0, hbuf, DD);
    }

    k_ln<<<dim3((unsigned)M), dim3(64), 0, stream>>>(hbuf, ln_g, ln_b, out);
}

// Round 17
// 300.909 us; speedup vs baseline: 1.2433x; 1.0370x over previous
//
#include <hip/hip_runtime.h>
#include <hip/hip_bf16.h>
#include <cstdint>
#include <cstddef>

#define BB 4
#define NN 1024
#define INDIM 128
#define DD 512
#define HH 8
#define EE 4
#define LL 3
#define HDIM 64

typedef __bf16 bf16x8 __attribute__((ext_vector_type(8)));
typedef _Float16 f16x8 __attribute__((ext_vector_type(8)));
typedef _Float16 h2 __attribute__((ext_vector_type(2)));
typedef float f32x4 __attribute__((ext_vector_type(4)));
typedef unsigned int u32x4 __attribute__((ext_vector_type(4)));

__device__ __forceinline__ unsigned short f2b(float f) {
    union { float f; unsigned int u; } v; v.f = f;
    unsigned int u = v.u;
    unsigned int r = (u + 0x7FFFu + ((u >> 16) & 1u)) >> 16;
    return (unsigned short)r;
}
__device__ __forceinline__ float b2f(unsigned int us) {
    union { unsigned int u; float f; } v; v.u = us << 16; return v.f;
}
__device__ __forceinline__ unsigned short h_bits(_Float16 h) {
    union { _Float16 h; unsigned short u; } v; v.h = h; return v.u;
}
__device__ __forceinline__ h2 u2h2(unsigned int u) {
    union { unsigned int u; h2 h; } v; v.u = u; return v.h;
}
__device__ __forceinline__ unsigned int pkrtz_u32(float a, float b) {
    auto h = __builtin_amdgcn_cvt_pkrtz(a, b);
    union { decltype(h) h; unsigned int u; } v; v.h = h; return v.u;
}

__device__ __forceinline__ void gl_lds16(const unsigned short* g, unsigned short* l) {
    __builtin_amdgcn_global_load_lds(
        (const __attribute__((address_space(1))) void*)g,
        (__attribute__((address_space(3))) void*)l, 16, 0, 0);
}

// ---------------- weight transpose+convert: W (K x N fp32) -> Wt (N x K bf16) ---------
__device__ __forceinline__ void transpose_tile_body(const float* __restrict__ src,
                                                    unsigned short* __restrict__ dst,
                                                    int K, int Nc) {
    __shared__ float tl[32][33];
    const int n0 = blockIdx.x * 32, k0 = blockIdx.y * 32;
    const int tx = threadIdx.x, ty = threadIdx.y;
#pragma unroll
    for (int r = 0; r < 4; r++) {
        int k = ty + r * 8;
        tl[k][tx] = src[(size_t)(k0 + k) * Nc + n0 + tx];
    }
    __syncthreads();
#pragma unroll
    for (int r = 0; r < 4; r++) {
        int n = ty + r * 8;
        dst[(size_t)(n0 + n) * K + k0 + tx] = f2b(tl[tx][n]);
    }
}

__global__ void k_transpose_in(const float* __restrict__ w, unsigned short* __restrict__ dst) {
    transpose_tile_body(w, dst, INDIM, DD);
}

__global__ void k_transpose_qkvo(const float* __restrict__ qw, const float* __restrict__ kw,
                                 const float* __restrict__ vw, const float* __restrict__ ow,
                                 unsigned short* __restrict__ dst) {
    int zz = blockIdx.z;
    int l = zz >> 2, tsel = zz & 3;
    const float* src = (tsel == 0) ? qw : (tsel == 1) ? kw : (tsel == 2) ? vw : ow;
    src += (size_t)l * DD * DD;
    transpose_tile_body(src, dst + (size_t)zz * DD * DD, DD, DD);
}

// ---------------- fp32 -> bf16 convert (x) ----------------
__global__ void k_convert(const float* __restrict__ src, unsigned short* __restrict__ dst,
                          long long n4) {
    long long stride = (long long)gridDim.x * blockDim.x;
    for (long long i = blockIdx.x * (long long)blockDim.x + threadIdx.x; i < n4; i += stride) {
        float4 v = reinterpret_cast<const float4*>(src)[i];
        uint2 o;
        o.x = (unsigned)f2b(v.x) | ((unsigned)f2b(v.y) << 16);
        o.y = (unsigned)f2b(v.z) | ((unsigned)f2b(v.w) << 16);
        reinterpret_cast<uint2*>(dst)[i] = o;
    }
}

// ---------------- edges fp32 -> tile-blocked F16 layout (ebt2) ----------------
// Tile = (b, it, jb): 8 KB of 16i x 64j x 4e f16; attn slot (c, lane) holds the quad
// for i = it*16 + (lane&15), j = jb*64 + (c>>1)*16 + (lane>>4)*4 + (c&1)*2 + q.
__global__ __launch_bounds__(256) void k_convert_e2(const float* __restrict__ src,
                                                    unsigned short* __restrict__ dst) {
    __shared__ unsigned short tl[4096];   // 8 KB tile
    const int tile = blockIdx.x;          // (b*64 + it)*16 + jb
    const int jb = tile & 15;
    const int it = (tile >> 4) & 63;
    const int b  = tile >> 10;
    const int tid = threadIdx.x;
    const int f4 = tid & 63;              // j_off within tile
    const int r0 = tid >> 6;              // 0..3
    const int jt = f4 >> 4, w16 = f4 & 15;
    const int lh = w16 >> 2, rr = w16 & 3;
    const int c = jt * 2 + (rr >> 1), q = rr & 1;
#pragma unroll
    for (int rd = 0; rd < 4; rd++) {
        const int lm = rd * 4 + r0;       // i within tile
        const float4 e = *reinterpret_cast<const float4*>(
            &src[(((size_t)b * NN + it * 16 + lm) * NN + jb * 64 + f4) * EE]);
        uint2 o;
        o.x = pkrtz_u32(e.x, e.y);
        o.y = pkrtz_u32(e.z, e.w);
        const int slot = c * 128 + (lh * 16 + lm) * 2 + q;   // uint2 units
        *reinterpret_cast<uint2*>(&tl[slot * 4]) = o;
    }
    __syncthreads();
    u32x4* g = reinterpret_cast<u32x4*>(dst) + (size_t)tile * 512;
    const u32x4* s = reinterpret_cast<const u32x4*>(tl);
    __builtin_nontemporal_store(s[tid], g + tid);
    __builtin_nontemporal_store(s[tid + 256], g + tid + 256);
}

// ---------------- bf16 MFMA GEMM: 128x64 tile, global_load_lds, m97 staging ----------
// 4 waves in 2x2 grid; each wave computes 64x32 via 4x2 fragments of 16x16x32.
// For z==2 with vt_out set, the epilogue writes V^T f16 (B,H,HD,N) directly
// (fuses the V-transpose kernel; lane's 4 r-values are consecutive n -> 8B stores).
__global__ __launch_bounds__(256) void k_gemm(
    const unsigned short* __restrict__ A,
    const unsigned short* __restrict__ Wt0, size_t wstride,
    const float* __restrict__ bias0, const float* __restrict__ bias1, const float* __restrict__ bias2,
    float* __restrict__ outf,
    unsigned short* __restrict__ outb, size_t ostride,
    unsigned short* __restrict__ vt_out,
    const float* __restrict__ resid,
    int Kd)
{
    __shared__ __align__(16) unsigned short As[128 * 32];
    __shared__ __align__(16) unsigned short Bs[64 * 32];
    const int tid = threadIdx.x;
    const int lane = tid & 63, wv = tid >> 6;
    const int wr = wv >> 1, wc = wv & 1;
    const int lm = lane & 15, lh = lane >> 4;
    const int m0 = blockIdx.y * 128, n0 = blockIdx.x * 64;
    const int z = blockIdx.z;
    const unsigned short* Wt = Wt0 + (size_t)z * wstride;
    const float* bias = (z == 0) ? bias0 : (z == 1) ? bias1 : bias2;

    f32x4 acc[4][2] = {};

    const int o0 = tid * 16;
    const int rowA = o0 >> 6, colA = (o0 & 63) >> 1;
    for (int k0 = 0; k0 < Kd; k0 += 32) {
        __syncthreads();
        gl_lds16(A  + (size_t)(m0 + rowA) * Kd + k0 + colA, As + (o0 >> 1));
        gl_lds16(A  + (size_t)(m0 + 64 + rowA) * Kd + k0 + colA, As + 2048 + (o0 >> 1));
        gl_lds16(Wt + (size_t)(n0 + rowA) * Kd + k0 + colA, Bs + (o0 >> 1));
        __syncthreads();

        bf16x8 af[4], bfg[2];
#pragma unroll
        for (int mi = 0; mi < 4; mi++)
            af[mi] = *reinterpret_cast<const bf16x8*>(&As[(wr * 64 + mi * 16 + lm) * 32 + lh * 8]);
#pragma unroll
        for (int nj = 0; nj < 2; nj++)
            bfg[nj] = *reinterpret_cast<const bf16x8*>(&Bs[(wc * 32 + nj * 16 + lm) * 32 + lh * 8]);
        __builtin_amdgcn_s_setprio(1);
#pragma unroll
        for (int mi = 0; mi < 4; mi++)
#pragma unroll
            for (int nj = 0; nj < 2; nj++)
                acc[mi][nj] = __builtin_amdgcn_mfma_f32_16x16x32_bf16(af[mi], bfg[nj], acc[mi][nj], 0, 0, 0);
        __builtin_amdgcn_s_setprio(0);
    }

    if (vt_out && z == 2) {
        // V epilogue: write transposed f16 vt[((b*H + h)*HD + d)*N + n]
        const int j = n0 + wc * 32 + lm;          // + nj*16
#pragma unroll
        for (int mi = 0; mi < 4; mi++) {
            const int i = m0 + wr * 64 + mi * 16 + lh * 4;   // + r (consecutive n)
            const int bb = i >> 10, n = i & (NN - 1);
#pragma unroll
            for (int nj = 0; nj < 2; nj++) {
                const int jj = j + nj * 16;
                const int hh = jj >> 6, d = jj & 63;
                union { unsigned short us[4]; uint2 u; } pk;
#pragma unroll
                for (int r = 0; r < 4; r++)
                    pk.us[r] = h_bits((_Float16)(acc[mi][nj][r] + bias[jj]));
                *reinterpret_cast<uint2*>(
                    &vt_out[(((size_t)bb * HH + hh) * HDIM + d) * NN + n]) = pk.u;
            }
        }
        return;
    }

#pragma unroll
    for (int mi = 0; mi < 4; mi++) {
#pragma unroll
        for (int nj = 0; nj < 2; nj++) {
#pragma unroll
            for (int r = 0; r < 4; r++) {
                int i = m0 + wr * 64 + mi * 16 + lh * 4 + r;
                int j = n0 + wc * 32 + nj * 16 + lm;
                float val = acc[mi][nj][r] + bias[j];
                size_t oidx = (size_t)i * DD + j;
                if (resid) val += resid[oidx];
                if (outf) outf[oidx] = val;
                if (outb) outb[(size_t)z * ostride + oidx] = f2b(val);
            }
        }
    }
}

// ---------------- fused attention G=2 (R11/R15 config): 32 q-rows/block --------------
// Grid 512 linear: xcd=lin&7, s=lin>>3, combo=xcd*2+(s>>5) = js*4+b, itg=s&31.
// Per j-iter: K,V loaded once, consumed by TWO independent QK/softmax/PV chains
// (g = 0,1 -> i-tiles itg*2, itg*2+1). E tiles (2 x 8 KB) DMA'd double-buffered.
template <int JS>
__global__ __launch_bounds__(512) void k_attn_g2(
    const unsigned short* __restrict__ qb,
    const unsigned short* __restrict__ kb,
    const unsigned short* __restrict__ vt,
    const unsigned short* __restrict__ ebt,  // f16 tile-blocked
    const float* __restrict__ ew,            // (L,E,H)
    const float* __restrict__ ebias,         // (L,H)
    int layer,
    unsigned short* __restrict__ outpb,      // (JS,B,N,D) bf16 partial O
    float2* __restrict__ mlp)                // (JS,B,H,N) partial (m,l)
{
    __shared__ __align__(16) unsigned short e_lds[2][2][4096];  // 32 KB
    __shared__ unsigned short p_lds[8][2][16 * 68];             // 34.8 KB
    const int lin = blockIdx.x;
    const int xcd = lin & 7;
    const int s   = lin >> 3;
    const int combo = xcd * 2 + (s >> 5);    // = js*4 + b
    const int itg = s & 31;
    const int b  = combo & 3;
    const int js = combo >> 2;
    const int tid = threadIdx.x;
    const int lane = tid & 63, wv = tid >> 6;
    const int h = wv;
    const int lm = lane & 15, lh = lane >> 4;

    const float LOG2E = 1.44269504f;
    const float ebh = ebias[layer * HH + h] * LOG2E;
    const float qscale = 0.125f * LOG2E;
    h2 w01, w23;
    w01.x = (_Float16)(ew[(layer * EE + 0) * HH + h] * LOG2E);
    w01.y = (_Float16)(ew[(layer * EE + 1) * HH + h] * LOG2E);
    w23.x = (_Float16)(ew[(layer * EE + 2) * HH + h] * LOG2E);
    w23.y = (_Float16)(ew[(layer * EE + 3) * HH + h] * LOG2E);

    bf16x8 aq[2][2];
#pragma unroll
    for (int g = 0; g < 2; g++) {
        const unsigned short* qrow =
            qb + ((size_t)(b * NN) + itg * 32 + g * 16 + lm) * DD + h * HDIM + lh * 8;
        aq[g][0] = *reinterpret_cast<const bf16x8*>(qrow);
        aq[g][1] = *reinterpret_cast<const bf16x8*>(qrow + 32);
    }

    f32x4 acc[2][4] = {};
    float m_run[2] = {-1e30f, -1e30f}, l_run[2] = {0.f, 0.f};

    constexpr int NITER = (NN / JS) / 64;
    const int jlo = js * (NN / JS);
    const int jb0 = jlo >> 6;
    const unsigned short* etile0 = ebt + ((size_t)((b * 64 + itg * 2 + 0) * 16 + jb0)) * 4096;
    const unsigned short* etile1 = ebt + ((size_t)((b * 64 + itg * 2 + 1) * 16 + jb0)) * 4096;
    const unsigned short* kptr = kb + ((size_t)(b * NN) + jlo + lm) * DD + h * HDIM + lh * 8;
    const unsigned short* vptr = vt + (((size_t)(b * HH) + h) * HDIM + lm) * NN + jlo + lh * 8;

    // prologue: DMA both g-tiles of j-tile 0
    gl_lds16(etile0 + tid * 8, &e_lds[0][0][tid * 8]);
    gl_lds16(etile1 + tid * 8, &e_lds[0][1][tid * 8]);
    __syncthreads();

#pragma unroll
    for (int i = 0; i < NITER; i++) {
        const int cur = i & 1;
        if (i + 1 < NITER) {
            gl_lds16(etile0 + (size_t)(i + 1) * 4096 + tid * 8, &e_lds[cur ^ 1][0][tid * 8]);
            gl_lds16(etile1 + (size_t)(i + 1) * 4096 + tid * 8, &e_lds[cur ^ 1][1][tid * 8]);
        }

        // ---- K and V for this j-tile (shared by both chains) ----
        bf16x8 kf[8];
        f16x8  vf[8];
#pragma unroll
        for (int jt = 0; jt < 4; jt++) {
            const unsigned short* kr = kptr + (size_t)i * 64 * DD + (size_t)jt * 16 * DD;
            kf[jt * 2]     = *reinterpret_cast<const bf16x8*>(kr);
            kf[jt * 2 + 1] = *reinterpret_cast<const bf16x8*>(kr + 32);
        }
#pragma unroll
        for (int kc = 0; kc < 2; kc++)
#pragma unroll
            for (int dt = 0; dt < 4; dt++)
                vf[kc * 4 + dt] = *reinterpret_cast<const f16x8*>(
                    vptr + (size_t)dt * 16 * NN + i * 64 + kc * 32);

        // ---- two independent chains ----
#pragma unroll
        for (int g = 0; g < 2; g++) {
            f32x4 sreg[4];
#pragma unroll
            for (int jt = 0; jt < 4; jt++) {
                f32x4 t = {};
                t = __builtin_amdgcn_mfma_f32_16x16x32_bf16(kf[jt * 2], aq[g][0], t, 0, 0, 0);
                t = __builtin_amdgcn_mfma_f32_16x16x32_bf16(kf[jt * 2 + 1], aq[g][1], t, 0, 0, 0);
                sreg[jt] = t;
            }

            float pv[16];
#pragma unroll
            for (int c = 0; c < 8; c++) {
                const uint4 ee = *reinterpret_cast<const uint4*>(
                    &e_lds[cur][g][(c * 64 + lane) * 8]);
                const int jt = c >> 1, r0 = (c & 1) * 2;
                pv[jt * 4 + r0] = fmaf(sreg[jt][r0], qscale,
                    __builtin_amdgcn_fdot2(u2h2(ee.x), w01,
                        __builtin_amdgcn_fdot2(u2h2(ee.y), w23, ebh, false), false));
                pv[jt * 4 + r0 + 1] = fmaf(sreg[jt][r0 + 1], qscale,
                    __builtin_amdgcn_fdot2(u2h2(ee.z), w01,
                        __builtin_amdgcn_fdot2(u2h2(ee.w), w23, ebh, false), false));
            }

            float mt = pv[0];
#pragma unroll
            for (int q = 1; q < 16; q++) mt = fmaxf(mt, pv[q]);
            mt = fmaxf(mt, __shfl_xor(mt, 16));
            mt = fmaxf(mt, __shfl_xor(mt, 32));
            float mn = fmaxf(m_run[g], mt);
            float corr = __builtin_amdgcn_exp2f(m_run[g] - mn);
            m_run[g] = mn;
            float ls = 0.f;
#pragma unroll
            for (int q = 0; q < 16; q++) {
                pv[q] = __builtin_amdgcn_exp2f(pv[q] - mn);
                ls += pv[q];
            }
            ls += __shfl_xor(ls, 16);
            ls += __shfl_xor(ls, 32);
            l_run[g] = l_run[g] * corr + ls;

#pragma unroll
            for (int jt = 0; jt < 4; jt++) {
                uint2 u;
                u.x = pkrtz_u32(pv[jt * 4 + 0], pv[jt * 4 + 1]);
                u.y = pkrtz_u32(pv[jt * 4 + 2], pv[jt * 4 + 3]);
                *reinterpret_cast<uint2*>(&p_lds[wv][g][lm * 68 + jt * 16 + lh * 4]) = u;
            }
#pragma unroll
            for (int dt = 0; dt < 4; dt++)
#pragma unroll
                for (int r = 0; r < 4; r++) acc[g][dt][r] *= corr;

#pragma unroll
            for (int kc = 0; kc < 2; kc++) {
                f16x8 pb = *reinterpret_cast<const f16x8*>(
                    &p_lds[wv][g][lm * 68 + kc * 32 + lh * 8]);
#pragma unroll
                for (int dt = 0; dt < 4; dt++)
                    acc[g][dt] = __builtin_amdgcn_mfma_f32_16x16x32_f16(
                        vf[kc * 4 + dt], pb, acc[g][dt], 0, 0, 0);
            }
        }

        __syncthreads();
    }

#pragma unroll
    for (int g = 0; g < 2; g++) {
        const int irow = itg * 32 + g * 16 + lm;
#pragma unroll
        for (int dt = 0; dt < 4; dt++) {
            union { unsigned short us[4]; uint2 u; } pk;
#pragma unroll
            for (int r = 0; r < 4; r++) pk.us[r] = f2b(acc[g][dt][r]);
            *reinterpret_cast<uint2*>(
                &outpb[((size_t)(js * BB + b) * NN + irow) * DD + h * HDIM + dt * 16 + lh * 4]) = pk.u;
        }
        if (lh == 0)
            mlp[((size_t)(js * BB + b) * HH + h) * NN + irow] = make_float2(m_run[g], l_run[g]);
    }
}

// ---------------- fallback fused attention (fp32 edges, unpipelined) ------------------
__global__ __launch_bounds__(512) void k_attn_f(
    const unsigned short* __restrict__ qb,
    const unsigned short* __restrict__ kb,
    const unsigned short* __restrict__ vt,
    const float* __restrict__ edges,
    const float* __restrict__ ew, const float* __restrict__ ebias,
    int layer,
    unsigned short* __restrict__ attnob)
{
    __shared__ unsigned short p_lds[8][16 * 68];
    const int b = blockIdx.y;
    const int i0 = blockIdx.x * 16;
    const int tid = threadIdx.x;
    const int lane = tid & 63, wv = tid >> 6;
    const int h = wv;
    const int lm = lane & 15, lh = lane >> 4;

    const float LOG2E = 1.44269504f;
    const float ew0 = ew[(layer * EE + 0) * HH + h] * LOG2E;
    const float ew1 = ew[(layer * EE + 1) * HH + h] * LOG2E;
    const float ew2 = ew[(layer * EE + 2) * HH + h] * LOG2E;
    const float ew3 = ew[(layer * EE + 3) * HH + h] * LOG2E;
    const float ebh = ebias[layer * HH + h] * LOG2E;
    const float qscale = 0.125f * LOG2E;

    const unsigned short* qrow = qb + ((size_t)(b * NN) + i0 + lm) * DD + h * HDIM + lh * 8;
    const bf16x8 aq0 = *reinterpret_cast<const bf16x8*>(qrow);
    const bf16x8 aq1 = *reinterpret_cast<const bf16x8*>(qrow + 32);

    f32x4 acc[4] = {};
    float m_run = -1e30f, l_run = 0.f;
    const float4* ef4 = (const float4*)edges;
    const size_t erowbase = ((size_t)b * NN + i0 + lm) * NN;

    for (int j0 = 0; j0 < NN; j0 += 64) {
        f32x4 sreg[4];
#pragma unroll
        for (int jt = 0; jt < 4; jt++) {
            const unsigned short* krow =
                kb + ((size_t)(b * NN) + j0 + jt * 16 + lm) * DD + h * HDIM + lh * 8;
            bf16x8 k0 = *reinterpret_cast<const bf16x8*>(krow);
            bf16x8 k1 = *reinterpret_cast<const bf16x8*>(krow + 32);
            f32x4 t = {};
            t = __builtin_amdgcn_mfma_f32_16x16x32_bf16(k0, aq0, t, 0, 0, 0);
            t = __builtin_amdgcn_mfma_f32_16x16x32_bf16(k1, aq1, t, 0, 0, 0);
            sreg[jt] = t;
        }
        float pv[16];
#pragma unroll
        for (int jt = 0; jt < 4; jt++) {
            const size_t jbase = erowbase + j0 + jt * 16 + lh * 4;
#pragma unroll
            for (int r = 0; r < 4; r++) {
                float4 e = ef4[jbase + r];
                pv[jt * 4 + r] = sreg[jt][r] * qscale
                    + e.x * ew0 + e.y * ew1 + e.z * ew2 + e.w * ew3 + ebh;
            }
        }
        float mt = pv[0];
#pragma unroll
        for (int q = 1; q < 16; q++) mt = fmaxf(mt, pv[q]);
        mt = fmaxf(mt, __shfl_xor(mt, 16));
        mt = fmaxf(mt, __shfl_xor(mt, 32));
        float mn = fmaxf(m_run, mt);
        float corr = __builtin_amdgcn_exp2f(m_run - mn);
        m_run = mn;
        float ls = 0.f;
#pragma unroll
        for (int q = 0; q < 16; q++) {
            pv[q] = __builtin_amdgcn_exp2f(pv[q] - mn);
            ls += pv[q];
        }
        ls += __shfl_xor(ls, 16);
        ls += __shfl_xor(ls, 32);
        l_run = l_run * corr + ls;
#pragma unroll
        for (int jt = 0; jt < 4; jt++) {
            uint2 u;
            u.x = pkrtz_u32(pv[jt * 4 + 0], pv[jt * 4 + 1]);
            u.y = pkrtz_u32(pv[jt * 4 + 2], pv[jt * 4 + 3]);
            *reinterpret_cast<uint2*>(&p_lds[wv][lm * 68 + jt * 16 + lh * 4]) = u;
        }
#pragma unroll
        for (int dt = 0; dt < 4; dt++)
#pragma unroll
            for (int r = 0; r < 4; r++) acc[dt][r] *= corr;
#pragma unroll
        for (int kc = 0; kc < 2; kc++) {
            f16x8 pb = *reinterpret_cast<const f16x8*>(&p_lds[wv][lm * 68 + kc * 32 + lh * 8]);
#pragma unroll
            for (int dt = 0; dt < 4; dt++) {
                f16x8 av = *reinterpret_cast<const f16x8*>(
                    vt + (((size_t)(b * HH) + h) * HDIM + dt * 16 + lm) * NN + j0 + kc * 32 + lh * 8);
                acc[dt] = __builtin_amdgcn_mfma_f32_16x16x32_f16(av, pb, acc[dt], 0, 0, 0);
            }
        }
    }
    const float inv = 1.f / l_run;
#pragma unroll
    for (int dt = 0; dt < 4; dt++) {
        union { unsigned short us[4]; uint2 u; } pk;
#pragma unroll
        for (int r = 0; r < 4; r++) pk.us[r] = f2b(acc[dt][r] * inv);
        *reinterpret_cast<uint2*>(
            &attnob[((size_t)(b * NN) + i0 + lm) * DD + h * HDIM + dt * 16 + lh * 4]) = pk.u;
    }
}

// ---------------- split-j reduce: combine JS bf16 partials -> bf16 attnob -------------
template <int JS>
__global__ __launch_bounds__(256) void k_attnred(
    const unsigned short* __restrict__ outpb, const float2* __restrict__ mlp,
    unsigned short* __restrict__ attnob)
{
    const int tid = blockIdx.x * 256 + threadIdx.x;   // (b,n,h,dc) dc = d/4
    const int dc = tid & 15;
    const int h = (tid >> 4) & 7;
    const int n = (tid >> 7) & (NN - 1);
    const int b = tid >> 17;
    float ms[JS], lsv[JS];
    float mstar = -1e30f;
#pragma unroll
    for (int s2 = 0; s2 < JS; s2++) {
        float2 ml = mlp[((size_t)(s2 * BB + b) * HH + h) * NN + n];
        ms[s2] = ml.x; lsv[s2] = ml.y;
        mstar = fmaxf(mstar, ml.x);
    }
    float lstar = 0.f;
    float o0 = 0.f, o1 = 0.f, o2 = 0.f, o3 = 0.f;
#pragma unroll
    for (int s2 = 0; s2 < JS; s2++) {
        float w = __builtin_amdgcn_exp2f(ms[s2] - mstar);
        lstar += w * lsv[s2];
        uint2 a = *reinterpret_cast<const uint2*>(
            &outpb[((size_t)(s2 * BB + b) * NN + n) * DD + h * HDIM + dc * 4]);
        o0 += w * b2f(a.x & 0xffffu); o1 += w * b2f(a.x >> 16);
        o2 += w * b2f(a.y & 0xffffu); o3 += w * b2f(a.y >> 16);
    }
    const float inv = 1.f / lstar;
    union { unsigned short us[4]; uint2 u; } pk;
    pk.us[0] = f2b(o0 * inv); pk.us[1] = f2b(o1 * inv);
    pk.us[2] = f2b(o2 * inv); pk.us[3] = f2b(o3 * inv);
    *reinterpret_cast<uint2*>(&attnob[((size_t)b * NN + n) * DD + h * HDIM + dc * 4]) = pk.u;
}

// ---------------- final layernorm: one wave per row ----------------
__global__ __launch_bounds__(64) void k_ln(const float* __restrict__ hbuf,
                                           const float* __restrict__ g,
                                           const float* __restrict__ bta,
                                           float* __restrict__ out) {
    const int row = blockIdx.x;
    const int lane = threadIdx.x;
    const float* hr = hbuf + (size_t)row * DD;
    float4 v0 = reinterpret_cast<const float4*>(hr)[lane * 2];
    float4 v1 = reinterpret_cast<const float4*>(hr)[lane * 2 + 1];
    float vals[8] = {v0.x, v0.y, v0.z, v0.w, v1.x, v1.y, v1.z, v1.w};
    float sum = 0.f, sq = 0.f;
#pragma unroll
    for (int q = 0; q < 8; q++) { sum += vals[q]; sq += vals[q] * vals[q]; }
#pragma unroll
    for (int m = 1; m <= 32; m <<= 1) {
        sum += __shfl_xor(sum, m);
        sq += __shfl_xor(sq, m);
    }
    float mu = sum * (1.f / DD);
    float var = sq * (1.f / DD) - mu * mu;
    float rs = rsqrtf(var + 1e-5f);
    const float* gp = g + lane * 8;
    const float* bp = bta + lane * 8;
    float* op = out + (size_t)row * DD + lane * 8;
#pragma unroll
    for (int q = 0; q < 8; q++) op[q] = (vals[q] - mu) * rs * gp[q] + bp[q];
}

extern "C" void kernel_launch(void* const* d_in, const int* in_sizes, int n_in,
                              void* d_out, int out_size, void* d_ws, size_t ws_size,
                              hipStream_t stream) {
    (void)in_sizes; (void)n_in; (void)out_size;
    const float* x     = (const float*)d_in[0];
    const float* edges = (const float*)d_in[1];
    const float* in_w  = (const float*)d_in[2];
    const float* in_b  = (const float*)d_in[3];
    const float* qw    = (const float*)d_in[4];
    const float* qbias = (const float*)d_in[5];
    const float* kw    = (const float*)d_in[6];
    const float* kbias = (const float*)d_in[7];
    const float* vw    = (const float*)d_in[8];
    const float* vbias = (const float*)d_in[9];
    const float* ow    = (const float*)d_in[10];
    const float* obias = (const float*)d_in[11];
    const float* ew    = (const float*)d_in[12];
    const float* ebias = (const float*)d_in[13];
    const float* ln_g  = (const float*)d_in[14];
    const float* ln_b  = (const float*)d_in[15];
    float* out = (float*)d_out;

    constexpr int JS = 4;
    char* ws = (char*)d_ws;
    size_t off = 0;
    auto alloc = [&](size_t bytes) -> void* {
        void* p = ws + off;
        off += (bytes + 255) & ~(size_t)255;
        return p;
    };
    const size_t M = (size_t)BB * NN;            // 4096
    float*          hbuf  = (float*)         alloc(M * DD * 4);
    unsigned short* hb    = (unsigned short*)alloc(M * DD * 2);
    unsigned short* xb    = (unsigned short*)alloc(M * INDIM * 2);
    unsigned short* wt_in = (unsigned short*)alloc((size_t)DD * INDIM * 2);
    unsigned short* wt    = (unsigned short*)alloc((size_t)12 * DD * DD * 2);
    unsigned short* qkvb  = (unsigned short*)alloc((size_t)3 * M * DD * 2);
    unsigned short* vtb   = (unsigned short*)alloc(M * DD * 2);
    unsigned short* attnob= (unsigned short*)alloc(M * DD * 2);
    const size_t edgeElems = (size_t)BB * NN * NN * EE;            // 16.8M
    unsigned short* ebt   = (unsigned short*)alloc(edgeElems * 2); // 33.5 MB tile-blocked f16
    const bool use_ebf = (off <= ws_size);
    unsigned short* outpb = (unsigned short*)alloc((size_t)JS * M * DD * 2);   // 16.8 MB
    float2*         mlp   = (float2*)        alloc((size_t)JS * BB * HH * NN * 8);
    const bool use_split = (off <= ws_size);
    const size_t BND = M * DD;

    // weight prep + input/edge conversion
    k_transpose_in<<<dim3(DD / 32, INDIM / 32), dim3(32, 8), 0, stream>>>(in_w, wt_in);
    k_transpose_qkvo<<<dim3(DD / 32, DD / 32, 12), dim3(32, 8), 0, stream>>>(qw, kw, vw, ow, wt);
    k_convert<<<dim3(512), dim3(256), 0, stream>>>(x, xb, (long long)(M * INDIM / 4));
    if (use_ebf && use_split)
        k_convert_e2<<<dim3(4096), dim3(256), 0, stream>>>(edges, ebt);

    // input projection: h = x @ in_w + in_b  (writes fp32 h and bf16 hb)
    k_gemm<<<dim3(8, 32, 1), dim3(256), 0, stream>>>(
        xb, wt_in, (size_t)0, in_b, in_b, in_b, hbuf, hb, (size_t)0,
        (unsigned short*)nullptr, (const float*)nullptr, INDIM);

    for (int l = 0; l < LL; l++) {
        // q,k,v projections; z==2 (V) writes transposed f16 vt directly (fused)
        k_gemm<<<dim3(8, 32, 3), dim3(256), 0, stream>>>(
            hb, wt + (size_t)(l * 4) * DD * DD, (size_t)DD * DD,
            qbias + l * DD, kbias + l * DD, vbias + l * DD,
            (float*)nullptr, qkvb, BND, vtb, (const float*)nullptr, DD);

        if (use_ebf && use_split) {
            k_attn_g2<JS><<<dim3(512), dim3(512), 0, stream>>>(
                qkvb, qkvb + BND, vtb, ebt, ew, ebias, l, outpb, mlp);
            k_attnred<JS><<<dim3((unsigned)(M * HH * 16 / 256)), dim3(256), 0, stream>>>(
                outpb, mlp, attnob);
        } else {
            k_attn_f<<<dim3(64, BB, 1), dim3(512), 0, stream>>>(
                qkvb, qkvb + BND, vtb, edges, ew, ebias, l, attnob);
        }

        k_gemm<<<dim3(8, 32, 1), dim3(256), 0, stream>>>(
            attnob, wt + (size_t)(l * 4 + 3) * DD * DD, (size_t)0,
            obias + l * DD, obias + l * DD, obias + l * DD,
            hbuf, hb, (size_t)0, (unsigned short*)nullptr, hbuf, DD);
    }

    k_ln<<<dim3((unsigned)M), dim3(64), 0, stream>>>(hbuf, ln_g, ln_b, out);
}

// Round 19
// 293.850 us; speedup vs baseline: 1.2732x; 1.0240x over previous
//
#include <hip/hip_runtime.h>
#include <hip/hip_bf16.h>
#include <cstdint>
#include <cstddef>

#define BB 4
#define NN 1024
#define INDIM 128
#define DD 512
#define HH 8
#define EE 4
#define LL 3
#define HDIM 64

typedef __bf16 bf16x8 __attribute__((ext_vector_type(8)));
typedef _Float16 f16x8 __attribute__((ext_vector_type(8)));
typedef _Float16 h2 __attribute__((ext_vector_type(2)));
typedef float f32x4 __attribute__((ext_vector_type(4)));
typedef unsigned int u32x4 __attribute__((ext_vector_type(4)));

__device__ __forceinline__ unsigned short f2b(float f) {
    union { float f; unsigned int u; } v; v.f = f;
    unsigned int u = v.u;
    unsigned int r = (u + 0x7FFFu + ((u >> 16) & 1u)) >> 16;
    return (unsigned short)r;
}
__device__ __forceinline__ float b2f(unsigned int us) {
    union { unsigned int u; float f; } v; v.u = us << 16; return v.f;
}
__device__ __forceinline__ unsigned short h_bits(_Float16 h) {
    union { _Float16 h; unsigned short u; } v; v.h = h; return v.u;
}
__device__ __forceinline__ h2 u2h2(unsigned int u) {
    union { unsigned int u; h2 h; } v; v.u = u; return v.h;
}
__device__ __forceinline__ unsigned int pkrtz_u32(float a, float b) {
    auto h = __builtin_amdgcn_cvt_pkrtz(a, b);
    union { decltype(h) h; unsigned int u; } v; v.h = h; return v.u;
}

__device__ __forceinline__ void gl_lds16(const unsigned short* g, unsigned short* l) {
    __builtin_amdgcn_global_load_lds(
        (const __attribute__((address_space(1))) void*)g,
        (__attribute__((address_space(3))) void*)l, 16, 0, 0);
}

// ---------------- weight transpose+convert: W (K x N fp32) -> Wt (N x K bf16) ---------
__device__ __forceinline__ void transpose_tile_body(const float* __restrict__ src,
                                                    unsigned short* __restrict__ dst,
                                                    int K, int Nc) {
    __shared__ float tl[32][33];
    const int n0 = blockIdx.x * 32, k0 = blockIdx.y * 32;
    const int tx = threadIdx.x, ty = threadIdx.y;
#pragma unroll
    for (int r = 0; r < 4; r++) {
        int k = ty + r * 8;
        tl[k][tx] = src[(size_t)(k0 + k) * Nc + n0 + tx];
    }
    __syncthreads();
#pragma unroll
    for (int r = 0; r < 4; r++) {
        int n = ty + r * 8;
        dst[(size_t)(n0 + n) * K + k0 + tx] = f2b(tl[tx][n]);
    }
}

__global__ void k_transpose_in(const float* __restrict__ w, unsigned short* __restrict__ dst) {
    transpose_tile_body(w, dst, INDIM, DD);
}

__global__ void k_transpose_qkvo(const float* __restrict__ qw, const float* __restrict__ kw,
                                 const float* __restrict__ vw, const float* __restrict__ ow,
                                 unsigned short* __restrict__ dst) {
    int zz = blockIdx.z;
    int l = zz >> 2, tsel = zz & 3;
    const float* src = (tsel == 0) ? qw : (tsel == 1) ? kw : (tsel == 2) ? vw : ow;
    src += (size_t)l * DD * DD;
    transpose_tile_body(src, dst + (size_t)zz * DD * DD, DD, DD);
}

// ---------------- fp32 -> bf16 convert (x) ----------------
__global__ void k_convert(const float* __restrict__ src, unsigned short* __restrict__ dst,
                          long long n4) {
    long long stride = (long long)gridDim.x * blockDim.x;
    for (long long i = blockIdx.x * (long long)blockDim.x + threadIdx.x; i < n4; i += stride) {
        float4 v = reinterpret_cast<const float4*>(src)[i];
        uint2 o;
        o.x = (unsigned)f2b(v.x) | ((unsigned)f2b(v.y) << 16);
        o.y = (unsigned)f2b(v.z) | ((unsigned)f2b(v.w) << 16);
        reinterpret_cast<uint2*>(dst)[i] = o;
    }
}

// ---------------- edges fp32 -> tile-blocked F16 layout (ebt2) ----------------
// Tile = (b, it, jb): 8 KB of 16i x 64j x 4e f16; attn slot (c, lane) holds the quad
// for i = it*16 + (lane&15), j = jb*64 + (c>>1)*16 + (lane>>4)*4 + (c&1)*2 + q.
__global__ __launch_bounds__(256) void k_convert_e2(const float* __restrict__ src,
                                                    unsigned short* __restrict__ dst) {
    __shared__ unsigned short tl[4096];   // 8 KB tile
    const int tile = blockIdx.x;          // (b*64 + it)*16 + jb
    const int jb = tile & 15;
    const int it = (tile >> 4) & 63;
    const int b  = tile >> 10;
    const int tid = threadIdx.x;
    const int f4 = tid & 63;              // j_off within tile
    const int r0 = tid >> 6;              // 0..3
    const int jt = f4 >> 4, w16 = f4 & 15;
    const int lh = w16 >> 2, rr = w16 & 3;
    const int c = jt * 2 + (rr >> 1), q = rr & 1;
#pragma unroll
    for (int rd = 0; rd < 4; rd++) {
        const int lm = rd * 4 + r0;       // i within tile
        const float4 e = *reinterpret_cast<const float4*>(
            &src[(((size_t)b * NN + it * 16 + lm) * NN + jb * 64 + f4) * EE]);
        uint2 o;
        o.x = pkrtz_u32(e.x, e.y);
        o.y = pkrtz_u32(e.z, e.w);
        const int slot = c * 128 + (lh * 16 + lm) * 2 + q;   // uint2 units
        *reinterpret_cast<uint2*>(&tl[slot * 4]) = o;
    }
    __syncthreads();
    u32x4* g = reinterpret_cast<u32x4*>(dst) + (size_t)tile * 512;
    const u32x4* s = reinterpret_cast<const u32x4*>(tl);
    __builtin_nontemporal_store(s[tid], g + tid);
    __builtin_nontemporal_store(s[tid + 256], g + tid + 256);
}

// ---------------- bf16 MFMA GEMM: 128x64 tile, global_load_lds, m97 staging ----------
// 4 waves in 2x2 grid; each wave computes 64x32 via 4x2 fragments of 16x16x32.
// z==2 with vt_out: epilogue writes V^T f16 (B,H,HD,N) directly (fused transpose).
// residb: optional bf16 residual added in epilogue (bf16 h-chain).
__global__ __launch_bounds__(256) void k_gemm(
    const unsigned short* __restrict__ A,
    const unsigned short* __restrict__ Wt0, size_t wstride,
    const float* __restrict__ bias0, const float* __restrict__ bias1, const float* __restrict__ bias2,
    unsigned short* __restrict__ outb, size_t ostride,
    unsigned short* __restrict__ vt_out,
    const unsigned short* __restrict__ residb,
    int Kd)
{
    __shared__ __align__(16) unsigned short As[128 * 32];
    __shared__ __align__(16) unsigned short Bs[64 * 32];
    const int tid = threadIdx.x;
    const int lane = tid & 63, wv = tid >> 6;
    const int wr = wv >> 1, wc = wv & 1;
    const int lm = lane & 15, lh = lane >> 4;
    const int m0 = blockIdx.y * 128, n0 = blockIdx.x * 64;
    const int z = blockIdx.z;
    const unsigned short* Wt = Wt0 + (size_t)z * wstride;
    const float* bias = (z == 0) ? bias0 : (z == 1) ? bias1 : bias2;

    f32x4 acc[4][2] = {};

    const int o0 = tid * 16;
    const int rowA = o0 >> 6, colA = (o0 & 63) >> 1;
    for (int k0 = 0; k0 < Kd; k0 += 32) {
        __syncthreads();
        gl_lds16(A  + (size_t)(m0 + rowA) * Kd + k0 + colA, As + (o0 >> 1));
        gl_lds16(A  + (size_t)(m0 + 64 + rowA) * Kd + k0 + colA, As + 2048 + (o0 >> 1));
        gl_lds16(Wt + (size_t)(n0 + rowA) * Kd + k0 + colA, Bs + (o0 >> 1));
        __syncthreads();

        bf16x8 af[4], bfg[2];
#pragma unroll
        for (int mi = 0; mi < 4; mi++)
            af[mi] = *reinterpret_cast<const bf16x8*>(&As[(wr * 64 + mi * 16 + lm) * 32 + lh * 8]);
#pragma unroll
        for (int nj = 0; nj < 2; nj++)
            bfg[nj] = *reinterpret_cast<const bf16x8*>(&Bs[(wc * 32 + nj * 16 + lm) * 32 + lh * 8]);
        __builtin_amdgcn_s_setprio(1);
#pragma unroll
        for (int mi = 0; mi < 4; mi++)
#pragma unroll
            for (int nj = 0; nj < 2; nj++)
                acc[mi][nj] = __builtin_amdgcn_mfma_f32_16x16x32_bf16(af[mi], bfg[nj], acc[mi][nj], 0, 0, 0);
        __builtin_amdgcn_s_setprio(0);
    }

    if (vt_out && z == 2) {
        // V epilogue: write transposed f16 vt[((b*H + h)*HD + d)*N + n]
        const int j = n0 + wc * 32 + lm;          // + nj*16
#pragma unroll
        for (int mi = 0; mi < 4; mi++) {
            const int i = m0 + wr * 64 + mi * 16 + lh * 4;   // + r (consecutive n)
            const int bb = i >> 10, n = i & (NN - 1);
#pragma unroll
            for (int nj = 0; nj < 2; nj++) {
                const int jj = j + nj * 16;
                const int hh = jj >> 6, d = jj & 63;
                union { unsigned short us[4]; uint2 u; } pk;
#pragma unroll
                for (int r = 0; r < 4; r++)
                    pk.us[r] = h_bits((_Float16)(acc[mi][nj][r] + bias[jj]));
                *reinterpret_cast<uint2*>(
                    &vt_out[(((size_t)bb * HH + hh) * HDIM + d) * NN + n]) = pk.u;
            }
        }
        return;
    }

#pragma unroll
    for (int mi = 0; mi < 4; mi++) {
#pragma unroll
        for (int nj = 0; nj < 2; nj++) {
#pragma unroll
            for (int r = 0; r < 4; r++) {
                int i = m0 + wr * 64 + mi * 16 + lh * 4 + r;
                int j = n0 + wc * 32 + nj * 16 + lm;
                float val = acc[mi][nj][r] + bias[j];
                size_t oidx = (size_t)i * DD + j;
                if (residb) val += b2f(residb[oidx]);
                outb[(size_t)z * ostride + oidx] = f2b(val);
            }
        }
    }
}

// ---------------- fused attention G=2 (R11/R15 config): 32 q-rows/block --------------
// Grid 512 linear: xcd=lin&7, s=lin>>3, combo=xcd*2+(s>>5) = js*4+b, itg=s&31.
// Per j-iter: K,V loaded once, consumed by TWO independent QK/softmax/PV chains
// (g = 0,1 -> i-tiles itg*2, itg*2+1). E tiles (2 x 8 KB) DMA'd double-buffered.
template <int JS>
__global__ __launch_bounds__(512) void k_attn_g2(
    const unsigned short* __restrict__ qb,
    const unsigned short* __restrict__ kb,
    const unsigned short* __restrict__ vt,
    const unsigned short* __restrict__ ebt,  // f16 tile-blocked
    const float* __restrict__ ew,            // (L,E,H)
    const float* __restrict__ ebias,         // (L,H)
    int layer,
    unsigned short* __restrict__ outpb,      // (JS,B,N,D) bf16 partial O
    float2* __restrict__ mlp)                // (JS,B,H,N) partial (m,l)
{
    __shared__ __align__(16) unsigned short e_lds[2][2][4096];  // 32 KB
    __shared__ unsigned short p_lds[8][2][16 * 68];             // 34.8 KB
    const int lin = blockIdx.x;
    const int xcd = lin & 7;
    const int s   = lin >> 3;
    const int combo = xcd * 2 + (s >> 5);    // = js*4 + b
    const int itg = s & 31;
    const int b  = combo & 3;
    const int js = combo >> 2;
    const int tid = threadIdx.x;
    const int lane = tid & 63, wv = tid >> 6;
    const int h = wv;
    const int lm = lane & 15, lh = lane >> 4;

    const float LOG2E = 1.44269504f;
    const float ebh = ebias[layer * HH + h] * LOG2E;
    const float qscale = 0.125f * LOG2E;
    h2 w01, w23;
    w01.x = (_Float16)(ew[(layer * EE + 0) * HH + h] * LOG2E);
    w01.y = (_Float16)(ew[(layer * EE + 1) * HH + h] * LOG2E);
    w23.x = (_Float16)(ew[(layer * EE + 2) * HH + h] * LOG2E);
    w23.y = (_Float16)(ew[(layer * EE + 3) * HH + h] * LOG2E);

    bf16x8 aq[2][2];
#pragma unroll
    for (int g = 0; g < 2; g++) {
        const unsigned short* qrow =
            qb + ((size_t)(b * NN) + itg * 32 + g * 16 + lm) * DD + h * HDIM + lh * 8;
        aq[g][0] = *reinterpret_cast<const bf16x8*>(qrow);
        aq[g][1] = *reinterpret_cast<const bf16x8*>(qrow + 32);
    }

    f32x4 acc[2][4] = {};
    float m_run[2] = {-1e30f, -1e30f}, l_run[2] = {0.f, 0.f};

    constexpr int NITER = (NN / JS) / 64;
    const int jlo = js * (NN / JS);
    const int jb0 = jlo >> 6;
    const unsigned short* etile0 = ebt + ((size_t)((b * 64 + itg * 2 + 0) * 16 + jb0)) * 4096;
    const unsigned short* etile1 = ebt + ((size_t)((b * 64 + itg * 2 + 1) * 16 + jb0)) * 4096;
    const unsigned short* kptr = kb + ((size_t)(b * NN) + jlo + lm) * DD + h * HDIM + lh * 8;
    const unsigned short* vptr = vt + (((size_t)(b * HH) + h) * HDIM + lm) * NN + jlo + lh * 8;

    // prologue: DMA both g-tiles of j-tile 0
    gl_lds16(etile0 + tid * 8, &e_lds[0][0][tid * 8]);
    gl_lds16(etile1 + tid * 8, &e_lds[0][1][tid * 8]);
    __syncthreads();

#pragma unroll
    for (int i = 0; i < NITER; i++) {
        const int cur = i & 1;
        if (i + 1 < NITER) {
            gl_lds16(etile0 + (size_t)(i + 1) * 4096 + tid * 8, &e_lds[cur ^ 1][0][tid * 8]);
            gl_lds16(etile1 + (size_t)(i + 1) * 4096 + tid * 8, &e_lds[cur ^ 1][1][tid * 8]);
        }

        // ---- K and V for this j-tile (shared by both chains) ----
        bf16x8 kf[8];
        f16x8  vf[8];
#pragma unroll
        for (int jt = 0; jt < 4; jt++) {
            const unsigned short* kr = kptr + (size_t)i * 64 * DD + (size_t)jt * 16 * DD;
            kf[jt * 2]     = *reinterpret_cast<const bf16x8*>(kr);
            kf[jt * 2 + 1] = *reinterpret_cast<const bf16x8*>(kr + 32);
        }
#pragma unroll
        for (int kc = 0; kc < 2; kc++)
#pragma unroll
            for (int dt = 0; dt < 4; dt++)
                vf[kc * 4 + dt] = *reinterpret_cast<const f16x8*>(
                    vptr + (size_t)dt * 16 * NN + i * 64 + kc * 32);

        // ---- two independent chains ----
#pragma unroll
        for (int g = 0; g < 2; g++) {
            f32x4 sreg[4];
#pragma unroll
            for (int jt = 0; jt < 4; jt++) {
                f32x4 t = {};
                t = __builtin_amdgcn_mfma_f32_16x16x32_bf16(kf[jt * 2], aq[g][0], t, 0, 0, 0);
                t = __builtin_amdgcn_mfma_f32_16x16x32_bf16(kf[jt * 2 + 1], aq[g][1], t, 0, 0, 0);
                sreg[jt] = t;
            }

            float pv[16];
#pragma unroll
            for (int c = 0; c < 8; c++) {
                const uint4 ee = *reinterpret_cast<const uint4*>(
                    &e_lds[cur][g][(c * 64 + lane) * 8]);
                const int jt = c >> 1, r0 = (c & 1) * 2;
                pv[jt * 4 + r0] = fmaf(sreg[jt][r0], qscale,
                    __builtin_amdgcn_fdot2(u2h2(ee.x), w01,
                        __builtin_amdgcn_fdot2(u2h2(ee.y), w23, ebh, false), false));
                pv[jt * 4 + r0 + 1] = fmaf(sreg[jt][r0 + 1], qscale,
                    __builtin_amdgcn_fdot2(u2h2(ee.z), w01,
                        __builtin_amdgcn_fdot2(u2h2(ee.w), w23, ebh, false), false));
            }

            float mt = pv[0];
#pragma unroll
            for (int q = 1; q < 16; q++) mt = fmaxf(mt, pv[q]);
            mt = fmaxf(mt, __shfl_xor(mt, 16));
            mt = fmaxf(mt, __shfl_xor(mt, 32));
            float mn = fmaxf(m_run[g], mt);
            float corr = __builtin_amdgcn_exp2f(m_run[g] - mn);
            m_run[g] = mn;
            float ls = 0.f;
#pragma unroll
            for (int q = 0; q < 16; q++) {
                pv[q] = __builtin_amdgcn_exp2f(pv[q] - mn);
                ls += pv[q];
            }
            ls += __shfl_xor(ls, 16);
            ls += __shfl_xor(ls, 32);
            l_run[g] = l_run[g] * corr + ls;

#pragma unroll
            for (int jt = 0; jt < 4; jt++) {
                uint2 u;
                u.x = pkrtz_u32(pv[jt * 4 + 0], pv[jt * 4 + 1]);
                u.y = pkrtz_u32(pv[jt * 4 + 2], pv[jt * 4 + 3]);
                *reinterpret_cast<uint2*>(&p_lds[wv][g][lm * 68 + jt * 16 + lh * 4]) = u;
            }
#pragma unroll
            for (int dt = 0; dt < 4; dt++)
#pragma unroll
                for (int r = 0; r < 4; r++) acc[g][dt][r] *= corr;

#pragma unroll
            for (int kc = 0; kc < 2; kc++) {
                f16x8 pb = *reinterpret_cast<const f16x8*>(
                    &p_lds[wv][g][lm * 68 + kc * 32 + lh * 8]);
#pragma unroll
                for (int dt = 0; dt < 4; dt++)
                    acc[g][dt] = __builtin_amdgcn_mfma_f32_16x16x32_f16(
                        vf[kc * 4 + dt], pb, acc[g][dt], 0, 0, 0);
            }
        }

        __syncthreads();
    }

#pragma unroll
    for (int g = 0; g < 2; g++) {
        const int irow = itg * 32 + g * 16 + lm;
#pragma unroll
        for (int dt = 0; dt < 4; dt++) {
            union { unsigned short us[4]; uint2 u; } pk;
#pragma unroll
            for (int r = 0; r < 4; r++) pk.us[r] = f2b(acc[g][dt][r]);
            *reinterpret_cast<uint2*>(
                &outpb[((size_t)(js * BB + b) * NN + irow) * DD + h * HDIM + dt * 16 + lh * 4]) = pk.u;
        }
        if (lh == 0)
            mlp[((size_t)(js * BB + b) * HH + h) * NN + irow] = make_float2(m_run[g], l_run[g]);
    }
}

// ---------------- split-j reduce: combine JS bf16 partials -> bf16 attnob -------------
template <int JS>
__global__ __launch_bounds__(256) void k_attnred(
    const unsigned short* __restrict__ outpb, const float2* __restrict__ mlp,
    unsigned short* __restrict__ attnob)
{
    const int tid = blockIdx.x * 256 + threadIdx.x;   // (b,n,h,dc) dc = d/4
    const int dc = tid & 15;
    const int h = (tid >> 4) & 7;
    const int n = (tid >> 7) & (NN - 1);
    const int b = tid >> 17;
    float ms[JS], lsv[JS];
    float mstar = -1e30f;
#pragma unroll
    for (int s2 = 0; s2 < JS; s2++) {
        float2 ml = mlp[((size_t)(s2 * BB + b) * HH + h) * NN + n];
        ms[s2] = ml.x; lsv[s2] = ml.y;
        mstar = fmaxf(mstar, ml.x);
    }
    float lstar = 0.f;
    float o0 = 0.f, o1 = 0.f, o2 = 0.f, o3 = 0.f;
#pragma unroll
    for (int s2 = 0; s2 < JS; s2++) {
        float w = __builtin_amdgcn_exp2f(ms[s2] - mstar);
        lstar += w * lsv[s2];
        uint2 a = *reinterpret_cast<const uint2*>(
            &outpb[((size_t)(s2 * BB + b) * NN + n) * DD + h * HDIM + dc * 4]);
        o0 += w * b2f(a.x & 0xffffu); o1 += w * b2f(a.x >> 16);
        o2 += w * b2f(a.y & 0xffffu); o3 += w * b2f(a.y >> 16);
    }
    const float inv = 1.f / lstar;
    union { unsigned short us[4]; uint2 u; } pk;
    pk.us[0] = f2b(o0 * inv); pk.us[1] = f2b(o1 * inv);
    pk.us[2] = f2b(o2 * inv); pk.us[3] = f2b(o3 * inv);
    *reinterpret_cast<uint2*>(&attnob[((size_t)b * NN + n) * DD + h * HDIM + dc * 4]) = pk.u;
}

// ---------------- final layernorm: one wave per row, bf16 input ----------------
__global__ __launch_bounds__(64) void k_ln(const unsigned short* __restrict__ hb,
                                           const float* __restrict__ g,
                                           const float* __restrict__ bta,
                                           float* __restrict__ out) {
    const int row = blockIdx.x;
    const int lane = threadIdx.x;
    const unsigned short* hr = hb + (size_t)row * DD + lane * 8;
    uint4 v = *reinterpret_cast<const uint4*>(hr);
    float vals[8] = { b2f(v.x & 0xffffu), b2f(v.x >> 16), b2f(v.y & 0xffffu), b2f(v.y >> 16),
                      b2f(v.z & 0xffffu), b2f(v.z >> 16), b2f(v.w & 0xffffu), b2f(v.w >> 16) };
    float sum = 0.f, sq = 0.f;
#pragma unroll
    for (int q = 0; q < 8; q++) { sum += vals[q]; sq += vals[q] * vals[q]; }
#pragma unroll
    for (int m = 1; m <= 32; m <<= 1) {
        sum += __shfl_xor(sum, m);
        sq += __shfl_xor(sq, m);
    }
    float mu = sum * (1.f / DD);
    float var = sq * (1.f / DD) - mu * mu;
    float rs = rsqrtf(var + 1e-5f);
    const float* gp = g + lane * 8;
    const float* bp = bta + lane * 8;
    float* op = out + (size_t)row * DD + lane * 8;
#pragma unroll
    for (int q = 0; q < 8; q++) op[q] = (vals[q] - mu) * rs * gp[q] + bp[q];
}

extern "C" void kernel_launch(void* const* d_in, const int* in_sizes, int n_in,
                              void* d_out, int out_size, void* d_ws, size_t ws_size,
                              hipStream_t stream) {
    (void)in_sizes; (void)n_in; (void)out_size;
    const float* x     = (const float*)d_in[0];
    const float* edges = (const float*)d_in[1];
    const float* in_w  = (const float*)d_in[2];
    const float* in_b  = (const float*)d_in[3];
    const float* qw    = (const float*)d_in[4];
    const float* qbias = (const float*)d_in[5];
    const float* kw    = (const float*)d_in[6];
    const float* kbias = (const float*)d_in[7];
    const float* vw    = (const float*)d_in[8];
    const float* vbias = (const float*)d_in[9];
    const float* ow    = (const float*)d_in[10];
    const float* obias = (const float*)d_in[11];
    const float* ew    = (const float*)d_in[12];
    const float* ebias = (const float*)d_in[13];
    const float* ln_g  = (const float*)d_in[14];
    const float* ln_b  = (const float*)d_in[15];
    float* out = (float*)d_out;

    constexpr int JS = 4;
    char* ws = (char*)d_ws;
    size_t off = 0;
    auto alloc = [&](size_t bytes) -> void* {
        void* p = ws + off;
        off += (bytes + 255) & ~(size_t)255;
        return p;
    };
    const size_t M = (size_t)BB * NN;            // 4096
    unsigned short* hb    = (unsigned short*)alloc(M * DD * 2);
    unsigned short* xb    = (unsigned short*)alloc(M * INDIM * 2);
    unsigned short* wt_in = (unsigned short*)alloc((size_t)DD * INDIM * 2);
    unsigned short* wt    = (unsigned short*)alloc((size_t)12 * DD * DD * 2);
    unsigned short* qkvb  = (unsigned short*)alloc((size_t)3 * M * DD * 2);
    unsigned short* vtb   = (unsigned short*)alloc(M * DD * 2);
    unsigned short* attnob= (unsigned short*)alloc(M * DD * 2);
    const size_t edgeElems = (size_t)BB * NN * NN * EE;            // 16.8M
    unsigned short* ebt   = (unsigned short*)alloc(edgeElems * 2); // 33.5 MB tile-blocked f16
    unsigned short* outpb = (unsigned short*)alloc((size_t)JS * M * DD * 2);   // 16.8 MB
    float2*         mlp   = (float2*)        alloc((size_t)JS * BB * HH * NN * 8);
    const size_t BND = M * DD;

    // weight prep + input/edge conversion
    k_transpose_in<<<dim3(DD / 32, INDIM / 32), dim3(32, 8), 0, stream>>>(in_w, wt_in);
    k_transpose_qkvo<<<dim3(DD / 32, DD / 32, 12), dim3(32, 8), 0, stream>>>(qw, kw, vw, ow, wt);
    k_convert<<<dim3(512), dim3(256), 0, stream>>>(x, xb, (long long)(M * INDIM / 4));
    k_convert_e2<<<dim3(4096), dim3(256), 0, stream>>>(edges, ebt);

    // input projection: hb = bf16(x @ in_w + in_b)
    k_gemm<<<dim3(8, 32, 1), dim3(256), 0, stream>>>(
        xb, wt_in, (size_t)0, in_b, in_b, in_b, hb, (size_t)0,
        (unsigned short*)nullptr, (const unsigned short*)nullptr, INDIM);

    for (int l = 0; l < LL; l++) {
        // q,k,v projections; z==2 (V) writes transposed f16 vt directly (fused)
        k_gemm<<<dim3(8, 32, 3), dim3(256), 0, stream>>>(
            hb, wt + (size_t)(l * 4) * DD * DD, (size_t)DD * DD,
            qbias + l * DD, kbias + l * DD, vbias + l * DD,
            qkvb, BND, vtb, (const unsigned short*)nullptr, DD);

        k_attn_g2<JS><<<dim3(512), dim3(512), 0, stream>>>(
            qkvb, qkvb + BND, vtb, ebt, ew, ebias, l, outpb, mlp);
        k_attnred<JS><<<dim3((unsigned)(M * HH * 16 / 256)), dim3(256), 0, stream>>>(
            outpb, mlp, attnob);

        // output projection + bf16 residual: hb = bf16(attno @ ow + ob + hb)
        k_gemm<<<dim3(8, 32, 1), dim3(256), 0, stream>>>(
            attnob, wt + (size_t)(l * 4 + 3) * DD * DD, (size_t)0,
            obias + l * DD, obias + l * DD, obias + l * DD,
            hb, (size_t)0, (unsigned short*)nullptr, hb, DD);
    }

    k_ln<<<dim3((unsigned)M), dim3(64), 0, stream>>>(hb, ln_g, ln_b, out);
}

// Round 20
// 290.525 us; speedup vs baseline: 1.2877x; 1.0114x over previous
//
#include <hip/hip_runtime.h>
#include <hip/hip_bf16.h>
#include <cstdint>
#include <cstddef>

#define BB 4
#define NN 1024
#define INDIM 128
#define DD 512
#define HH 8
#define EE 4
#define LL 3
#define HDIM 64

typedef __bf16 bf16x8 __attribute__((ext_vector_type(8)));
typedef _Float16 f16x8 __attribute__((ext_vector_type(8)));
typedef _Float16 h2 __attribute__((ext_vector_type(2)));
typedef float f32x4 __attribute__((ext_vector_type(4)));
typedef unsigned int u32x4 __attribute__((ext_vector_type(4)));

__device__ __forceinline__ unsigned short f2b(float f) {
    union { float f; unsigned int u; } v; v.f = f;
    unsigned int u = v.u;
    unsigned int r = (u + 0x7FFFu + ((u >> 16) & 1u)) >> 16;
    return (unsigned short)r;
}
__device__ __forceinline__ float b2f(unsigned int us) {
    union { unsigned int u; float f; } v; v.u = us << 16; return v.f;
}
__device__ __forceinline__ unsigned short h_bits(_Float16 h) {
    union { _Float16 h; unsigned short u; } v; v.h = h; return v.u;
}
__device__ __forceinline__ h2 u2h2(unsigned int u) {
    union { unsigned int u; h2 h; } v; v.u = u; return v.h;
}
__device__ __forceinline__ unsigned int pkrtz_u32(float a, float b) {
    auto h = __builtin_amdgcn_cvt_pkrtz(a, b);
    union { decltype(h) h; unsigned int u; } v; v.h = h; return v.u;
}

__device__ __forceinline__ void gl_lds16(const unsigned short* g, unsigned short* l) {
    __builtin_amdgcn_global_load_lds(
        (const __attribute__((address_space(1))) void*)g,
        (__attribute__((address_space(3))) void*)l, 16, 0, 0);
}

// ---------------- weight transpose+convert: W (K x N fp32) -> Wt (N x K bf16) ---------
__device__ __forceinline__ void transpose_tile_body(const float* __restrict__ src,
                                                    unsigned short* __restrict__ dst,
                                                    int K, int Nc) {
    __shared__ float tl[32][33];
    const int n0 = blockIdx.x * 32, k0 = blockIdx.y * 32;
    const int tx = threadIdx.x, ty = threadIdx.y;
#pragma unroll
    for (int r = 0; r < 4; r++) {
        int k = ty + r * 8;
        tl[k][tx] = src[(size_t)(k0 + k) * Nc + n0 + tx];
    }
    __syncthreads();
#pragma unroll
    for (int r = 0; r < 4; r++) {
        int n = ty + r * 8;
        dst[(size_t)(n0 + n) * K + k0 + tx] = f2b(tl[tx][n]);
    }
}

__global__ void k_transpose_in(const float* __restrict__ w, unsigned short* __restrict__ dst) {
    transpose_tile_body(w, dst, INDIM, DD);
}

__global__ void k_transpose_qkvo(const float* __restrict__ qw, const float* __restrict__ kw,
                                 const float* __restrict__ vw, const float* __restrict__ ow,
                                 unsigned short* __restrict__ dst) {
    int zz = blockIdx.z;
    int l = zz >> 2, tsel = zz & 3;
    const float* src = (tsel == 0) ? qw : (tsel == 1) ? kw : (tsel == 2) ? vw : ow;
    src += (size_t)l * DD * DD;
    transpose_tile_body(src, dst + (size_t)zz * DD * DD, DD, DD);
}

// ---------------- fp32 -> bf16 convert (x) ----------------
__global__ void k_convert(const float* __restrict__ src, unsigned short* __restrict__ dst,
                          long long n4) {
    long long stride = (long long)gridDim.x * blockDim.x;
    for (long long i = blockIdx.x * (long long)blockDim.x + threadIdx.x; i < n4; i += stride) {
        float4 v = reinterpret_cast<const float4*>(src)[i];
        uint2 o;
        o.x = (unsigned)f2b(v.x) | ((unsigned)f2b(v.y) << 16);
        o.y = (unsigned)f2b(v.z) | ((unsigned)f2b(v.w) << 16);
        reinterpret_cast<uint2*>(dst)[i] = o;
    }
}

// ---------------- edges fp32 -> tile-blocked F16 layout (ebt2) ----------------
// Tile = (b, it, jb): 8 KB of 16i x 64j x 4e f16; attn slot (c, lane) holds the quad
// for i = it*16 + (lane&15), j = jb*64 + (c>>1)*16 + (lane>>4)*4 + (c&1)*2 + q.
__global__ __launch_bounds__(256) void k_convert_e2(const float* __restrict__ src,
                                                    unsigned short* __restrict__ dst) {
    __shared__ unsigned short tl[4096];   // 8 KB tile
    const int tile = blockIdx.x;          // (b*64 + it)*16 + jb
    const int jb = tile & 15;
    const int it = (tile >> 4) & 63;
    const int b  = tile >> 10;
    const int tid = threadIdx.x;
    const int f4 = tid & 63;              // j_off within tile
    const int r0 = tid >> 6;              // 0..3
    const int jt = f4 >> 4, w16 = f4 & 15;
    const int lh = w16 >> 2, rr = w16 & 3;
    const int c = jt * 2 + (rr >> 1), q = rr & 1;
#pragma unroll
    for (int rd = 0; rd < 4; rd++) {
        const int lm = rd * 4 + r0;       // i within tile
        const float4 e = *reinterpret_cast<const float4*>(
            &src[(((size_t)b * NN + it * 16 + lm) * NN + jb * 64 + f4) * EE]);
        uint2 o;
        o.x = pkrtz_u32(e.x, e.y);
        o.y = pkrtz_u32(e.z, e.w);
        const int slot = c * 128 + (lh * 16 + lm) * 2 + q;   // uint2 units
        *reinterpret_cast<uint2*>(&tl[slot * 4]) = o;
    }
    __syncthreads();
    u32x4* g = reinterpret_cast<u32x4*>(dst) + (size_t)tile * 512;
    const u32x4* s = reinterpret_cast<const u32x4*>(tl);
    __builtin_nontemporal_store(s[tid], g + tid);
    __builtin_nontemporal_store(s[tid + 256], g + tid + 256);
}

// ---------------- bf16 MFMA GEMM: 128x64 tile, global_load_lds, m97 staging ----------
// 4 waves in 2x2 grid; each wave computes 64x32 via 4x2 fragments of 16x16x32.
// z==2 with vt_out: epilogue writes V^T f16 (B,H,HD,N) directly (fused transpose).
// residb: optional bf16 residual added in epilogue (bf16 h-chain).
__global__ __launch_bounds__(256) void k_gemm(
    const unsigned short* __restrict__ A,
    const unsigned short* __restrict__ Wt0, size_t wstride,
    const float* __restrict__ bias0, const float* __restrict__ bias1, const float* __restrict__ bias2,
    unsigned short* __restrict__ outb, size_t ostride,
    unsigned short* __restrict__ vt_out,
    const unsigned short* __restrict__ residb,
    int Kd)
{
    __shared__ __align__(16) unsigned short As[128 * 32];
    __shared__ __align__(16) unsigned short Bs[64 * 32];
    const int tid = threadIdx.x;
    const int lane = tid & 63, wv = tid >> 6;
    const int wr = wv >> 1, wc = wv & 1;
    const int lm = lane & 15, lh = lane >> 4;
    const int m0 = blockIdx.y * 128, n0 = blockIdx.x * 64;
    const int z = blockIdx.z;
    const unsigned short* Wt = Wt0 + (size_t)z * wstride;
    const float* bias = (z == 0) ? bias0 : (z == 1) ? bias1 : bias2;

    f32x4 acc[4][2] = {};

    const int o0 = tid * 16;
    const int rowA = o0 >> 6, colA = (o0 & 63) >> 1;
    for (int k0 = 0; k0 < Kd; k0 += 32) {
        __syncthreads();
        gl_lds16(A  + (size_t)(m0 + rowA) * Kd + k0 + colA, As + (o0 >> 1));
        gl_lds16(A  + (size_t)(m0 + 64 + rowA) * Kd + k0 + colA, As + 2048 + (o0 >> 1));
        gl_lds16(Wt + (size_t)(n0 + rowA) * Kd + k0 + colA, Bs + (o0 >> 1));
        __syncthreads();

        bf16x8 af[4], bfg[2];
#pragma unroll
        for (int mi = 0; mi < 4; mi++)
            af[mi] = *reinterpret_cast<const bf16x8*>(&As[(wr * 64 + mi * 16 + lm) * 32 + lh * 8]);
#pragma unroll
        for (int nj = 0; nj < 2; nj++)
            bfg[nj] = *reinterpret_cast<const bf16x8*>(&Bs[(wc * 32 + nj * 16 + lm) * 32 + lh * 8]);
        __builtin_amdgcn_s_setprio(1);
#pragma unroll
        for (int mi = 0; mi < 4; mi++)
#pragma unroll
            for (int nj = 0; nj < 2; nj++)
                acc[mi][nj] = __builtin_amdgcn_mfma_f32_16x16x32_bf16(af[mi], bfg[nj], acc[mi][nj], 0, 0, 0);
        __builtin_amdgcn_s_setprio(0);
    }

    if (vt_out && z == 2) {
        // V epilogue: write transposed f16 vt[((b*H + h)*HD + d)*N + n]
        const int j = n0 + wc * 32 + lm;          // + nj*16
#pragma unroll
        for (int mi = 0; mi < 4; mi++) {
            const int i = m0 + wr * 64 + mi * 16 + lh * 4;   // + r (consecutive n)
            const int bb = i >> 10, n = i & (NN - 1);
#pragma unroll
            for (int nj = 0; nj < 2; nj++) {
                const int jj = j + nj * 16;
                const int hh = jj >> 6, d = jj & 63;
                union { unsigned short us[4]; uint2 u; } pk;
#pragma unroll
                for (int r = 0; r < 4; r++)
                    pk.us[r] = h_bits((_Float16)(acc[mi][nj][r] + bias[jj]));
                *reinterpret_cast<uint2*>(
                    &vt_out[(((size_t)bb * HH + hh) * HDIM + d) * NN + n]) = pk.u;
            }
        }
        return;
    }

#pragma unroll
    for (int mi = 0; mi < 4; mi++) {
#pragma unroll
        for (int nj = 0; nj < 2; nj++) {
#pragma unroll
            for (int r = 0; r < 4; r++) {
                int i = m0 + wr * 64 + mi * 16 + lh * 4 + r;
                int j = n0 + wc * 32 + nj * 16 + lm;
                float val = acc[mi][nj][r] + bias[j];
                size_t oidx = (size_t)i * DD + j;
                if (residb) val += b2f(residb[oidx]);
                outb[(size_t)z * ostride + oidx] = f2b(val);
            }
        }
    }
}

// ---------------- fused attention G=2 (R11/R15 config): 32 q-rows/block --------------
// Grid 512 linear: xcd=lin&7, s=lin>>3, combo=xcd*2+(s>>5) = js*4+b, itg=s&31.
// Per j-iter: K,V loaded once, consumed by TWO independent QK/softmax/PV chains
// (g = 0,1 -> i-tiles itg*2, itg*2+1). E tiles (2 x 8 KB) DMA'd double-buffered.
template <int JS>
__global__ __launch_bounds__(512) void k_attn_g2(
    const unsigned short* __restrict__ qb,
    const unsigned short* __restrict__ kb,
    const unsigned short* __restrict__ vt,
    const unsigned short* __restrict__ ebt,  // f16 tile-blocked
    const float* __restrict__ ew,            // (L,E,H)
    const float* __restrict__ ebias,         // (L,H)
    int layer,
    unsigned short* __restrict__ outpb,      // (JS,B,N,D) bf16 partial O
    float2* __restrict__ mlp)                // (JS,B,H,N) partial (m,l)
{
    __shared__ __align__(16) unsigned short e_lds[2][2][4096];  // 32 KB
    __shared__ unsigned short p_lds[8][2][16 * 68];             // 34.8 KB
    const int lin = blockIdx.x;
    const int xcd = lin & 7;
    const int s   = lin >> 3;
    const int combo = xcd * 2 + (s >> 5);    // = js*4 + b
    const int itg = s & 31;
    const int b  = combo & 3;
    const int js = combo >> 2;
    const int tid = threadIdx.x;
    const int lane = tid & 63, wv = tid >> 6;
    const int h = wv;
    const int lm = lane & 15, lh = lane >> 4;

    const float LOG2E = 1.44269504f;
    const float ebh = ebias[layer * HH + h] * LOG2E;
    const float qscale = 0.125f * LOG2E;
    h2 w01, w23;
    w01.x = (_Float16)(ew[(layer * EE + 0) * HH + h] * LOG2E);
    w01.y = (_Float16)(ew[(layer * EE + 1) * HH + h] * LOG2E);
    w23.x = (_Float16)(ew[(layer * EE + 2) * HH + h] * LOG2E);
    w23.y = (_Float16)(ew[(layer * EE + 3) * HH + h] * LOG2E);

    bf16x8 aq[2][2];
#pragma unroll
    for (int g = 0; g < 2; g++) {
        const unsigned short* qrow =
            qb + ((size_t)(b * NN) + itg * 32 + g * 16 + lm) * DD + h * HDIM + lh * 8;
        aq[g][0] = *reinterpret_cast<const bf16x8*>(qrow);
        aq[g][1] = *reinterpret_cast<const bf16x8*>(qrow + 32);
    }

    f32x4 acc[2][4] = {};
    float m_run[2] = {-1e30f, -1e30f}, l_run[2] = {0.f, 0.f};

    constexpr int NITER = (NN / JS) / 64;
    const int jlo = js * (NN / JS);
    const int jb0 = jlo >> 6;
    const unsigned short* etile0 = ebt + ((size_t)((b * 64 + itg * 2 + 0) * 16 + jb0)) * 4096;
    const unsigned short* etile1 = ebt + ((size_t)((b * 64 + itg * 2 + 1) * 16 + jb0)) * 4096;
    const unsigned short* kptr = kb + ((size_t)(b * NN) + jlo + lm) * DD + h * HDIM + lh * 8;
    const unsigned short* vptr = vt + (((size_t)(b * HH) + h) * HDIM + lm) * NN + jlo + lh * 8;

    // prologue: DMA both g-tiles of j-tile 0
    gl_lds16(etile0 + tid * 8, &e_lds[0][0][tid * 8]);
    gl_lds16(etile1 + tid * 8, &e_lds[0][1][tid * 8]);
    __syncthreads();

#pragma unroll
    for (int i = 0; i < NITER; i++) {
        const int cur = i & 1;
        if (i + 1 < NITER) {
            gl_lds16(etile0 + (size_t)(i + 1) * 4096 + tid * 8, &e_lds[cur ^ 1][0][tid * 8]);
            gl_lds16(etile1 + (size_t)(i + 1) * 4096 + tid * 8, &e_lds[cur ^ 1][1][tid * 8]);
        }

        // ---- K and V for this j-tile (shared by both chains) ----
        bf16x8 kf[8];
        f16x8  vf[8];
#pragma unroll
        for (int jt = 0; jt < 4; jt++) {
            const unsigned short* kr = kptr + (size_t)i * 64 * DD + (size_t)jt * 16 * DD;
            kf[jt * 2]     = *reinterpret_cast<const bf16x8*>(kr);
            kf[jt * 2 + 1] = *reinterpret_cast<const bf16x8*>(kr + 32);
        }
#pragma unroll
        for (int kc = 0; kc < 2; kc++)
#pragma unroll
            for (int dt = 0; dt < 4; dt++)
                vf[kc * 4 + dt] = *reinterpret_cast<const f16x8*>(
                    vptr + (size_t)dt * 16 * NN + i * 64 + kc * 32);

        // ---- two independent chains ----
#pragma unroll
        for (int g = 0; g < 2; g++) {
            f32x4 sreg[4];
#pragma unroll
            for (int jt = 0; jt < 4; jt++) {
                f32x4 t = {};
                t = __builtin_amdgcn_mfma_f32_16x16x32_bf16(kf[jt * 2], aq[g][0], t, 0, 0, 0);
                t = __builtin_amdgcn_mfma_f32_16x16x32_bf16(kf[jt * 2 + 1], aq[g][1], t, 0, 0, 0);
                sreg[jt] = t;
            }

            float pv[16];
#pragma unroll
            for (int c = 0; c < 8; c++) {
                const uint4 ee = *reinterpret_cast<const uint4*>(
                    &e_lds[cur][g][(c * 64 + lane) * 8]);
                const int jt = c >> 1, r0 = (c & 1) * 2;
                pv[jt * 4 + r0] = fmaf(sreg[jt][r0], qscale,
                    __builtin_amdgcn_fdot2(u2h2(ee.x), w01,
                        __builtin_amdgcn_fdot2(u2h2(ee.y), w23, ebh, false), false));
                pv[jt * 4 + r0 + 1] = fmaf(sreg[jt][r0 + 1], qscale,
                    __builtin_amdgcn_fdot2(u2h2(ee.z), w01,
                        __builtin_amdgcn_fdot2(u2h2(ee.w), w23, ebh, false), false));
            }

            float mt = pv[0];
#pragma unroll
            for (int q = 1; q < 16; q++) mt = fmaxf(mt, pv[q]);
            mt = fmaxf(mt, __shfl_xor(mt, 16));
            mt = fmaxf(mt, __shfl_xor(mt, 32));
            float mn = fmaxf(m_run[g], mt);
            float corr = __builtin_amdgcn_exp2f(m_run[g] - mn);
            m_run[g] = mn;
            float ls = 0.f;
#pragma unroll
            for (int q = 0; q < 16; q++) {
                pv[q] = __builtin_amdgcn_exp2f(pv[q] - mn);
                ls += pv[q];
            }
            ls += __shfl_xor(ls, 16);
            ls += __shfl_xor(ls, 32);
            l_run[g] = l_run[g] * corr + ls;

#pragma unroll
            for (int jt = 0; jt < 4; jt++) {
                uint2 u;
                u.x = pkrtz_u32(pv[jt * 4 + 0], pv[jt * 4 + 1]);
                u.y = pkrtz_u32(pv[jt * 4 + 2], pv[jt * 4 + 3]);
                *reinterpret_cast<uint2*>(&p_lds[wv][g][lm * 68 + jt * 16 + lh * 4]) = u;
            }
#pragma unroll
            for (int dt = 0; dt < 4; dt++)
#pragma unroll
                for (int r = 0; r < 4; r++) acc[g][dt][r] *= corr;

#pragma unroll
            for (int kc = 0; kc < 2; kc++) {
                f16x8 pb = *reinterpret_cast<const f16x8*>(
                    &p_lds[wv][g][lm * 68 + kc * 32 + lh * 8]);
#pragma unroll
                for (int dt = 0; dt < 4; dt++)
                    acc[g][dt] = __builtin_amdgcn_mfma_f32_16x16x32_f16(
                        vf[kc * 4 + dt], pb, acc[g][dt], 0, 0, 0);
            }
        }

        __syncthreads();
    }

#pragma unroll
    for (int g = 0; g < 2; g++) {
        const int irow = itg * 32 + g * 16 + lm;
#pragma unroll
        for (int dt = 0; dt < 4; dt++) {
            union { unsigned short us[4]; uint2 u; } pk;
#pragma unroll
            for (int r = 0; r < 4; r++) pk.us[r] = f2b(acc[g][dt][r]);
            *reinterpret_cast<uint2*>(
                &outpb[((size_t)(js * BB + b) * NN + irow) * DD + h * HDIM + dt * 16 + lh * 4]) = pk.u;
        }
        if (lh == 0)
            mlp[((size_t)(js * BB + b) * HH + h) * NN + irow] = make_float2(m_run[g], l_run[g]);
    }
}

// ---------------- split-j reduce: combine JS bf16 partials -> bf16 attnob -------------
// One thread per 8 output elements (uint4 loads per split).
template <int JS>
__global__ __launch_bounds__(256) void k_attnred(
    const unsigned short* __restrict__ outpb, const float2* __restrict__ mlp,
    unsigned short* __restrict__ attnob)
{
    const int tid = blockIdx.x * 256 + threadIdx.x;   // (b,n,h,dc) dc = d/8
    const int dc = tid & 7;
    const int h = (tid >> 3) & 7;
    const int n = (tid >> 6) & (NN - 1);
    const int b = tid >> 16;
    float ms[JS], lsv[JS];
    float mstar = -1e30f;
#pragma unroll
    for (int s2 = 0; s2 < JS; s2++) {
        float2 ml = mlp[((size_t)(s2 * BB + b) * HH + h) * NN + n];
        ms[s2] = ml.x; lsv[s2] = ml.y;
        mstar = fmaxf(mstar, ml.x);
    }
    float lstar = 0.f;
    float o[8] = {0.f, 0.f, 0.f, 0.f, 0.f, 0.f, 0.f, 0.f};
#pragma unroll
    for (int s2 = 0; s2 < JS; s2++) {
        float w = __builtin_amdgcn_exp2f(ms[s2] - mstar);
        lstar += w * lsv[s2];
        uint4 a = *reinterpret_cast<const uint4*>(
            &outpb[((size_t)(s2 * BB + b) * NN + n) * DD + h * HDIM + dc * 8]);
        o[0] += w * b2f(a.x & 0xffffu); o[1] += w * b2f(a.x >> 16);
        o[2] += w * b2f(a.y & 0xffffu); o[3] += w * b2f(a.y >> 16);
        o[4] += w * b2f(a.z & 0xffffu); o[5] += w * b2f(a.z >> 16);
        o[6] += w * b2f(a.w & 0xffffu); o[7] += w * b2f(a.w >> 16);
    }
    const float inv = 1.f / lstar;
    union { unsigned short us[8]; uint4 u; } pk;
#pragma unroll
    for (int q = 0; q < 8; q++) pk.us[q] = f2b(o[q] * inv);
    *reinterpret_cast<uint4*>(&attnob[((size_t)b * NN + n) * DD + h * HDIM + dc * 8]) = pk.u;
}

// ---------------- final layernorm: 4 waves per block, one row per wave, bf16 input ----
__global__ __launch_bounds__(256) void k_ln(const unsigned short* __restrict__ hb,
                                            const float* __restrict__ g,
                                            const float* __restrict__ bta,
                                            float* __restrict__ out) {
    const int row = blockIdx.x * 4 + (threadIdx.x >> 6);
    const int lane = threadIdx.x & 63;
    const unsigned short* hr = hb + (size_t)row * DD + lane * 8;
    uint4 v = *reinterpret_cast<const uint4*>(hr);
    float vals[8] = { b2f(v.x & 0xffffu), b2f(v.x >> 16), b2f(v.y & 0xffffu), b2f(v.y >> 16),
                      b2f(v.z & 0xffffu), b2f(v.z >> 16), b2f(v.w & 0xffffu), b2f(v.w >> 16) };
    float sum = 0.f, sq = 0.f;
#pragma unroll
    for (int q = 0; q < 8; q++) { sum += vals[q]; sq += vals[q] * vals[q]; }
#pragma unroll
    for (int m = 1; m <= 32; m <<= 1) {
        sum += __shfl_xor(sum, m);
        sq += __shfl_xor(sq, m);
    }
    float mu = sum * (1.f / DD);
    float var = sq * (1.f / DD) - mu * mu;
    float rs = rsqrtf(var + 1e-5f);
    const float* gp = g + lane * 8;
    const float* bp = bta + lane * 8;
    float* op = out + (size_t)row * DD + lane * 8;
#pragma unroll
    for (int q = 0; q < 8; q++) op[q] = (vals[q] - mu) * rs * gp[q] + bp[q];
}

extern "C" void kernel_launch(void* const* d_in, const int* in_sizes, int n_in,
                              void* d_out, int out_size, void* d_ws, size_t ws_size,
                              hipStream_t stream) {
    (void)in_sizes; (void)n_in; (void)out_size; (void)ws_size;
    const float* x     = (const float*)d_in[0];
    const float* edges = (const float*)d_in[1];
    const float* in_w  = (const float*)d_in[2];
    const float* in_b  = (const float*)d_in[3];
    const float* qw    = (const float*)d_in[4];
    const float* qbias = (const float*)d_in[5];
    const float* kw    = (const float*)d_in[6];
    const float* kbias = (const float*)d_in[7];
    const float* vw    = (const float*)d_in[8];
    const float* vbias = (const float*)d_in[9];
    const float* ow    = (const float*)d_in[10];
    const float* obias = (const float*)d_in[11];
    const float* ew    = (const float*)d_in[12];
    const float* ebias = (const float*)d_in[13];
    const float* ln_g  = (const float*)d_in[14];
    const float* ln_b  = (const float*)d_in[15];
    float* out = (float*)d_out;

    constexpr int JS = 4;
    char* ws = (char*)d_ws;
    size_t off = 0;
    auto alloc = [&](size_t bytes) -> void* {
        void* p = ws + off;
        off += (bytes + 255) & ~(size_t)255;
        return p;
    };
    const size_t M = (size_t)BB * NN;            // 4096
    unsigned short* hb    = (unsigned short*)alloc(M * DD * 2);
    unsigned short* xb    = (unsigned short*)alloc(M * INDIM * 2);
    unsigned short* wt_in = (unsigned short*)alloc((size_t)DD * INDIM * 2);
    unsigned short* wt    = (unsigned short*)alloc((size_t)12 * DD * DD * 2);
    unsigned short* qkvb  = (unsigned short*)alloc((size_t)3 * M * DD * 2);
    unsigned short* vtb   = (unsigned short*)alloc(M * DD * 2);
    unsigned short* attnob= (unsigned short*)alloc(M * DD * 2);
    const size_t edgeElems = (size_t)BB * NN * NN * EE;            // 16.8M
    unsigned short* ebt   = (unsigned short*)alloc(edgeElems * 2); // 33.5 MB tile-blocked f16
    unsigned short* outpb = (unsigned short*)alloc((size_t)JS * M * DD * 2);   // 16.8 MB
    float2*         mlp   = (float2*)        alloc((size_t)JS * BB * HH * NN * 8);
    const size_t BND = M * DD;

    // weight prep + input/edge conversion
    k_transpose_in<<<dim3(DD / 32, INDIM / 32), dim3(32, 8), 0, stream>>>(in_w, wt_in);
    k_transpose_qkvo<<<dim3(DD / 32, DD / 32, 12), dim3(32, 8), 0, stream>>>(qw, kw, vw, ow, wt);
    k_convert<<<dim3(512), dim3(256), 0, stream>>>(x, xb, (long long)(M * INDIM / 4));
    k_convert_e2<<<dim3(4096), dim3(256), 0, stream>>>(edges, ebt);

    // input projection: hb = bf16(x @ in_w + in_b)
    k_gemm<<<dim3(8, 32, 1), dim3(256), 0, stream>>>(
        xb, wt_in, (size_t)0, in_b, in_b, in_b, hb, (size_t)0,
        (unsigned short*)nullptr, (const unsigned short*)nullptr, INDIM);

    for (int l = 0; l < LL; l++) {
        // q,k,v projections; z==2 (V) writes transposed f16 vt directly (fused)
        k_gemm<<<dim3(8, 32, 3), dim3(256), 0, stream>>>(
            hb, wt + (size_t)(l * 4) * DD * DD, (size_t)DD * DD,
            qbias + l * DD, kbias + l * DD, vbias + l * DD,
            qkvb, BND, vtb, (const unsigned short*)nullptr, DD);

        k_attn_g2<JS><<<dim3(512), dim3(512), 0, stream>>>(
            qkvb, qkvb + BND, vtb, ebt, ew, ebias, l, outpb, mlp);
        k_attnred<JS><<<dim3((unsigned)(M * HH * 8 / 256)), dim3(256), 0, stream>>>(
            outpb, mlp, attnob);

        // output projection + bf16 residual: hb = bf16(attno @ ow + ob + hb)
        k_gemm<<<dim3(8, 32, 1), dim3(256), 0, stream>>>(
            attnob, wt + (size_t)(l * 4 + 3) * DD * DD, (size_t)0,
            obias + l * DD, obias + l * DD, obias + l * DD,
            hb, (size_t)0, (unsigned short*)nullptr, hb, DD);
    }

    k_ln<<<dim3((unsigned)(M / 4)), dim3(256), 0, stream>>>(hb, ln_g, ln_b, out);
}